// Round 7
// baseline (5913.553 us; speedup 1.0000x reference)
//
#include <hip/hip_runtime.h>
#include <math.h>

#define D 512
#define MROWS 32768
#define CCOLS 8192
#define K2 1536
#define NT 24            // K-tiles of 64
#define NSPLIT 2
#define CT_PER_SPLIT 16  // 4096 cols / 256
#define NTILES_TOTAL (NT * CT_PER_SPLIT)
#define TAU 2.0e-4f

typedef __attribute__((ext_vector_type(8))) short short8v;
typedef __attribute__((ext_vector_type(4))) float f32x4;

__device__ __forceinline__ unsigned short f2bf_rne(float f) {
    unsigned u = __float_as_uint(f);
    unsigned r = ((u >> 16) & 1u) + 0x7FFFu;
    return (unsigned short)((u + r) >> 16);
}
__device__ __forceinline__ float bf2f(unsigned short h) {
    return __uint_as_float(((unsigned)h) << 16);
}

__device__ __forceinline__ void gload_lds16(const void* gsrc, void* ldst) {
    __builtin_amdgcn_global_load_lds(
        (const __attribute__((address_space(1))) unsigned int*)gsrc,
        (__attribute__((address_space(3))) unsigned int*)ldst, 16, 0, 0);
}

// ---------- prep: codebook -> inv_norm + E2 = [hi(e_n) | lo(e_n) | hi(e_n)] ----------
__global__ __launch_bounds__(64) void prep_embed_kernel(
    const float* __restrict__ embed, unsigned short* __restrict__ E2,
    float* __restrict__ inv_norm) {
    int cb = blockIdx.x, lane = threadIdx.x;
    const float4* r4 = reinterpret_cast<const float4*>(embed + (size_t)cb * D);
    float4 a = r4[lane], b = r4[lane + 64];
    float ss = a.x*a.x + a.y*a.y + a.z*a.z + a.w*a.w
             + b.x*b.x + b.y*b.y + b.z*b.z + b.w*b.w;
#pragma unroll
    for (int off = 32; off > 0; off >>= 1) ss += __shfl_xor(ss, off);
    float inv = 1.0f / fmaxf(sqrtf(ss), 1e-12f);
    if (lane == 0) inv_norm[cb] = inv;
    float ea[4] = {a.x*inv, a.y*inv, a.z*inv, a.w*inv};
    float eb[4] = {b.x*inv, b.y*inv, b.z*inv, b.w*inv};
    ushort4 ha, la, hb, lb;
    { for (int j=0;j<4;++j) (&ha.x)[j] = f2bf_rne(ea[j]); }
    { for (int j=0;j<4;++j) (&la.x)[j] = f2bf_rne(ea[j] - bf2f((&ha.x)[j])); }
    { for (int j=0;j<4;++j) (&hb.x)[j] = f2bf_rne(eb[j]); }
    { for (int j=0;j<4;++j) (&lb.x)[j] = f2bf_rne(eb[j] - bf2f((&hb.x)[j])); }
    unsigned short* row = E2 + (size_t)cb * K2;
    int k = lane * 4;
    *(ushort4*)&row[k]          = ha;  // hi  at [0,512)
    *(ushort4*)&row[256 + k]    = hb;
    *(ushort4*)&row[512 + k]    = la;  // lo  at [512,1024)
    *(ushort4*)&row[768 + k]    = lb;
    *(ushort4*)&row[1024 + k]   = ha;  // hi  at [1024,1536)
    *(ushort4*)&row[1280 + k]   = hb;
}

// ---------- prep: x -> X2 = [hi(x) | hi(x) | lo(x)] ----------
__global__ __launch_bounds__(64) void prep_x_kernel(
    const float* __restrict__ x, unsigned short* __restrict__ X2) {
    int rb = blockIdx.x, lane = threadIdx.x;
    const float4* r4 = reinterpret_cast<const float4*>(x + (size_t)rb * D);
    float4 a = r4[lane], b = r4[lane + 64];
    float ea[4] = {a.x, a.y, a.z, a.w};
    float eb[4] = {b.x, b.y, b.z, b.w};
    ushort4 ha, la, hb, lb;
    { for (int j=0;j<4;++j) (&ha.x)[j] = f2bf_rne(ea[j]); }
    { for (int j=0;j<4;++j) (&la.x)[j] = f2bf_rne(ea[j] - bf2f((&ha.x)[j])); }
    { for (int j=0;j<4;++j) (&hb.x)[j] = f2bf_rne(eb[j]); }
    { for (int j=0;j<4;++j) (&lb.x)[j] = f2bf_rne(eb[j] - bf2f((&hb.x)[j])); }
    unsigned short* row = X2 + (size_t)rb * K2;
    int k = lane * 4;
    *(ushort4*)&row[k]        = ha;   // hi
    *(ushort4*)&row[256 + k]  = hb;
    *(ushort4*)&row[512 + k]  = ha;   // hi again
    *(ushort4*)&row[768 + k]  = hb;
    *(ushort4*)&row[1024 + k] = la;   // lo
    *(ushort4*)&row[1280 + k] = lb;
}

// producer: stage one full 256x64 half (A for pw=0, B for pw=1) of tile T.
// dst granule i*64+lane, row=g>>3, swizzled src granule (g&7)^(row&7) --
// identical mapping to the consumer-side read swizzle (both-sides rule).
__device__ __forceinline__ void stage_tile(
    const unsigned short* __restrict__ X2, const unsigned short* __restrict__ E2,
    unsigned short* AsB, unsigned short* BsB,
    size_t grow0, int ct0s, int kt, int pw, int lane) {
    if (pw == 0) {
#pragma unroll
        for (int i = 0; i < 32; ++i) {
            int g = i * 64 + lane;
            int row = g >> 3;
            int gsrc = (g & 7) ^ (row & 7);
            gload_lds16(X2 + (grow0 + row) * (size_t)K2 + kt + gsrc * 8,
                        AsB + i * 512);
        }
    } else {
#pragma unroll
        for (int i = 0; i < 32; ++i) {
            int g = i * 64 + lane;
            int row = g >> 3;
            int gsrc = (g & 7) ^ (row & 7);
            gload_lds16(E2 + (size_t)(ct0s + row) * K2 + kt + gsrc * 8,
                        BsB + i * 512);
        }
    }
}

// ---------- 256x256-tile bf16 GEMM + per-row top-2, producer/consumer ----------
// 640 threads = 10 waves: w0-7 compute (4M x 2N, 64x128 each), w8-9 stage.
// One __syncthreads per K-tile: its implicit vmcnt(0) is the producers'
// staging drain and a no-op for consumers (they issue no VMEM).
__global__ __launch_bounds__(640, 1) void gemm_topk3_kernel(
    const unsigned short* __restrict__ X2, const unsigned short* __restrict__ E2,
    float4* __restrict__ partials) {
    __shared__ __align__(16) unsigned short As[2][256 * 64];
    __shared__ __align__(16) unsigned short Bs[2][256 * 64];
    __shared__ float smv1[256], smv2[256];
    __shared__ int   smi[256];

    const int tid  = threadIdx.x;
    const int lane = tid & 63;
    const int w    = tid >> 6;          // 0..9
    const int wm   = w >> 1;            // consumers: 0..3 (row group of 64)
    const int wn   = w & 1;             // consumers: 0..1 (col group of 128)
    const int c    = lane & 15;
    const int q    = lane >> 4;

    // bijective XCD-contiguous mapping: XCD x owns logical [x*32, x*32+32)
    const int bid     = blockIdx.x;
    const int logical = (bid & 7) * 32 + (bid >> 3);
    const int split   = logical >> 7;        // 0..1
    const int rowtile = logical & 127;       // 0..127
    const size_t grow0 = (size_t)rowtile * 256;
    const int col0     = split * (CT_PER_SPLIT * 256);

    float v1[16], v2[16]; int i1[16];
#pragma unroll
    for (int s = 0; s < 16; ++s) { v1[s] = -3.0e38f; v2[s] = -3.0e38f; i1[s] = 0; }

    if (w >= 8) {
        // ---------------- producer waves ----------------
        const int pw = w & 1;      // w8 -> A, w9 -> B
        stage_tile(X2, E2, &As[0][0], &Bs[0][0], grow0, col0, 0, pw, lane);
        __syncthreads();           // window 0 ready (vmcnt(0) implicit)
        for (int T = 0; T < NTILES_TOTAL; ++T) {
            int Tn = T + 1;
            if (Tn < NTILES_TOTAL) {
                int kt   = (Tn % NT) * 64;
                int ct0s = col0 + (Tn / NT) * 256;
                int bufn = Tn & 1;
                stage_tile(X2, E2, &As[bufn][0], &Bs[bufn][0],
                           grow0, ct0s, kt, pw, lane);
            }
            __syncthreads();       // end of window T (drains producer loads)
        }
    } else {
        // ---------------- consumer waves ----------------
        __syncthreads();           // wait for tile 0
        int T = 0;
        for (int cti = 0; cti < CT_PER_SPLIT; ++cti) {
            const int ct0 = col0 + cti * 256;
            f32x4 acc[4][8];
#pragma unroll
            for (int m = 0; m < 4; ++m)
#pragma unroll
                for (int j = 0; j < 8; ++j) acc[m][j] = (f32x4){0.f, 0.f, 0.f, 0.f};

            for (int t = 0; t < NT; ++t, ++T) {
                const int buf = T & 1;
                // A fragments for this tile: 8 x ds_read_b128
                short8v af[4][2];
#pragma unroll
                for (int m = 0; m < 4; ++m)
#pragma unroll
                    for (int kk = 0; kk < 2; ++kk) {
                        int row = wm * 64 + m * 16 + c;
                        int g   = ((kk * 4 + q) ^ (row & 7));
                        af[m][kk] = *(const short8v*)&As[buf][row * 64 + g * 8];
                    }
#pragma unroll
                for (int ph = 0; ph < 4; ++ph) {
                    short8v bf[2][2];
#pragma unroll
                    for (int n = 0; n < 2; ++n)
#pragma unroll
                        for (int kk = 0; kk < 2; ++kk) {
                            int rb = wn * 128 + ph * 32 + n * 16 + c;
                            int g  = ((kk * 4 + q) ^ (rb & 7));
                            bf[n][kk] = *(const short8v*)&Bs[buf][rb * 64 + g * 8];
                        }
                    __builtin_amdgcn_s_setprio(1);
#pragma unroll
                    for (int kk = 0; kk < 2; ++kk)
#pragma unroll
                        for (int m = 0; m < 4; ++m)
#pragma unroll
                            for (int n = 0; n < 2; ++n)
                                acc[m][ph * 2 + n] = __builtin_amdgcn_mfma_f32_16x16x32_bf16(
                                    af[m][kk], bf[n][kk], acc[m][ph * 2 + n], 0, 0, 0);
                    __builtin_amdgcn_s_setprio(0);
                }
                __syncthreads();   // end of window T
            }

            // fold this 256-col tile into running per-lane top-2
#pragma unroll
            for (int m = 0; m < 4; ++m)
#pragma unroll
                for (int j = 0; j < 8; ++j) {
                    int col = ct0 + wn * 128 + (j >> 1) * 32 + (j & 1) * 16 + c;
#pragma unroll
                    for (int r = 0; r < 4; ++r) {
                        float sv = acc[m][j][r];
                        int slot = m * 4 + r;
                        if (sv > v1[slot]) { v2[slot] = v1[slot]; v1[slot] = sv; i1[slot] = col; }
                        else if (sv > v2[slot]) v2[slot] = sv;
                    }
                }
        }

        // cross-lane merge over the 16 col-lanes (rows fixed per (q,slot))
#pragma unroll
        for (int s = 0; s < 16; ++s) {
            float a1 = v1[s], a2 = v2[s]; int ai = i1[s];
#pragma unroll
            for (int off = 1; off < 16; off <<= 1) {
                float o1 = __shfl_xor(a1, off);
                float o2 = __shfl_xor(a2, off);
                int   oi = __shfl_xor(ai, off);
                if (o1 > a1 || (o1 == a1 && oi < ai)) {
                    a2 = fmaxf(a1, o2); a1 = o1; ai = oi;
                } else {
                    a2 = fmaxf(a2, o1);   // tie with larger idx -> gap 0 -> fallback
                }
            }
            v1[s] = a1; v2[s] = a2; i1[s] = ai;
        }
        // wn=1 wave publishes for the wn-merge
        if (c == 0 && wn == 1) {
#pragma unroll
            for (int s = 0; s < 16; ++s) {
                int li = wm * 64 + q * 16 + s;
                smv1[li] = v1[s]; smv2[li] = v2[s]; smi[li] = i1[s];
            }
        }
    }

    __syncthreads();   // common: producers 386th, consumers 386th
    if (w < 8 && c == 0 && wn == 0) {
#pragma unroll
        for (int s = 0; s < 16; ++s) {
            int li = wm * 64 + q * 16 + s;
            float o1 = smv1[li], o2 = smv2[li]; int oi = smi[li];
            if (o1 > v1[s] || (o1 == v1[s] && oi < i1[s])) {
                v2[s] = fmaxf(v1[s], o2); v1[s] = o1; i1[s] = oi;
            } else {
                v2[s] = fmaxf(v2[s], o1);
            }
            int row = (int)grow0 + wm * 64 + (s >> 2) * 16 + q * 4 + (s & 3);
            partials[(size_t)row * 4 + split] =
                make_float4(v1[s], v2[s], __int_as_float(i1[s]), 0.f);
        }
    }
}

// ---------- combine split-partials, gap test, enqueue fallback ----------
__global__ __launch_bounds__(256) void combine_kernel(
    const float4* __restrict__ partials, int* __restrict__ ind,
    int* __restrict__ fb_count, int* __restrict__ fb_rows,
    unsigned long long* __restrict__ best) {
    int row = blockIdx.x * 256 + threadIdx.x;
    if (row >= MROWS) return;
    float g1 = -3.0e38f, g2 = -3.0e38f; int gi = 0;
#pragma unroll
    for (int s = 0; s < NSPLIT; ++s) {
        float4 p = partials[(size_t)row * 4 + s];
        if (p.x > g1 || (p.x == g1 && __float_as_int(p.z) < gi)) {
            g2 = fmaxf(g1, p.y); g1 = p.x; gi = __float_as_int(p.z);
        } else {
            g2 = fmaxf(g2, p.x);
        }
    }
    ind[row] = gi;
    if (g1 - g2 <= TAU) {
        int k = atomicAdd(fb_count, 1);
        fb_rows[k] = row;
        best[row] = 0ull;
    }
}

// ---------- exact f32 rescore for flagged rows ----------
__global__ __launch_bounds__(256) void fallback_kernel(
    const float* __restrict__ x, const float* __restrict__ embed,
    const float* __restrict__ inv_norm, const int* __restrict__ fb_count,
    const int* __restrict__ fb_rows, unsigned long long* __restrict__ best) {
    __shared__ float es[16][D];
    __shared__ float xs[D];
    const int t = threadIdx.x;
    const int c0 = blockIdx.x * 16;
    for (int i = t; i < 16 * 128; i += 256) {
        int col = i >> 7, f4 = i & 127;
        *(float4*)&es[col][f4 * 4] =
            *(const float4*)&embed[(size_t)(c0 + col) * D + f4 * 4];
    }
    const int nfb = *fb_count;
    const int col = t >> 4, s = t & 15;
    for (int ri = 0; ri < nfb; ++ri) {
        int row = fb_rows[ri];
        __syncthreads();
        if (t < 128)
            *(float4*)&xs[t * 4] = *(const float4*)&x[(size_t)row * D + t * 4];
        __syncthreads();
        float dot = 0.f;
        const float* ep = &es[col][s * 32];
        const float* xp = &xs[s * 32];
#pragma unroll
        for (int k = 0; k < 8; ++k) {
            float4 a = *(const float4*)&xp[k * 4];
            float4 b = *(const float4*)&ep[k * 4];
            dot = fmaf(a.x, b.x, fmaf(a.y, b.y, fmaf(a.z, b.z, fmaf(a.w, b.w, dot))));
        }
        dot += __shfl_xor(dot, 1); dot += __shfl_xor(dot, 2);
        dot += __shfl_xor(dot, 4); dot += __shfl_xor(dot, 8);
        if (s == 0) {
            float score = dot * inv_norm[c0 + col];
            unsigned fb = __float_as_uint(score);
            fb = (fb & 0x80000000u) ? ~fb : (fb | 0x80000000u);
            unsigned long long key = ((unsigned long long)fb << 32) |
                (unsigned long long)(0xFFFFFFFFu - (unsigned)(c0 + col));
            atomicMax(best + row, key);
        }
    }
}

__global__ void fbwrite_kernel(const int* __restrict__ fb_count,
                               const int* __restrict__ fb_rows,
                               const unsigned long long* __restrict__ best,
                               int* __restrict__ ind) {
    int n = *fb_count;
    for (int i = threadIdx.x; i < n; i += 256) {
        int row = fb_rows[i];
        unsigned long long k = best[row];
        ind[row] = (int)(0xFFFFFFFFu - (unsigned)(k & 0xFFFFFFFFull));
    }
}

// ---------- gather ----------
__global__ __launch_bounds__(128) void gather_kernel(
    const float* __restrict__ embed, const int* __restrict__ ind,
    float* __restrict__ out_q, float* __restrict__ out_i) {
    int row = blockIdx.x;
    int t = threadIdx.x;
    int idx = ind[row];
    const float4* src = reinterpret_cast<const float4*>(embed + (size_t)idx * D);
    float4* dst = reinterpret_cast<float4*>(out_q + (size_t)row * D);
    dst[t] = src[t];
    if (t == 0) out_i[row] = (float)idx;
}

// ================= legacy f32 path (used if ws too small) =================
#define BM 64
#define BN 128
#define BK 32
#define LDX (BM + 4)
#define LDE (BN + 4)

__global__ __launch_bounds__(64) void norm_kernel(const float* __restrict__ embed,
                                                  float* __restrict__ inv_norm) {
    int cb = blockIdx.x, lane = threadIdx.x;
    const float4* r4 = reinterpret_cast<const float4*>(embed + (size_t)cb * D);
    float4 a = r4[lane], b = r4[lane + 64];
    float s = a.x*a.x + a.y*a.y + a.z*a.z + a.w*a.w
            + b.x*b.x + b.y*b.y + b.z*b.z + b.w*b.w;
#pragma unroll
    for (int off = 32; off > 0; off >>= 1) s += __shfl_xor(s, off);
    if (lane == 0) inv_norm[cb] = 1.0f / fmaxf(sqrtf(s), 1e-12f);
}

__global__ __launch_bounds__(256) void gemm_argmax_kernel(
    const float* __restrict__ x, const float* __restrict__ embed,
    const float* __restrict__ inv_norm, int* __restrict__ ind, int C) {
    __shared__ float xs[BK][LDX];
    __shared__ float es[BK][LDE];
    const int tid = threadIdx.x;
    const int tx = tid & 15;
    const int ty = tid >> 4;
    const int row0 = blockIdx.x * BM;
    float bestv[4]; int besti[4];
#pragma unroll
    for (int i = 0; i < 4; ++i) { bestv[i] = -3.0e38f; besti[i] = 0; }
    for (int ct = 0; ct < C; ct += BN) {
        float acc[4][8];
#pragma unroll
        for (int i = 0; i < 4; ++i)
#pragma unroll
            for (int j = 0; j < 8; ++j) acc[i][j] = 0.0f;
        for (int kt = 0; kt < D; kt += BK) {
#pragma unroll
            for (int i = 0; i < 2; ++i) {
                int f = tid + i * 256;
                int r = f >> 3, kq = (f & 7) << 2;
                float4 v = *reinterpret_cast<const float4*>(
                    x + (size_t)(row0 + r) * D + kt + kq);
                xs[kq+0][r]=v.x; xs[kq+1][r]=v.y; xs[kq+2][r]=v.z; xs[kq+3][r]=v.w;
            }
#pragma unroll
            for (int i = 0; i < 4; ++i) {
                int f = tid + i * 256;
                int r = f >> 3, kq = (f & 7) << 2;
                float4 v = *reinterpret_cast<const float4*>(
                    embed + (size_t)(ct + r) * D + kt + kq);
                es[kq+0][r]=v.x; es[kq+1][r]=v.y; es[kq+2][r]=v.z; es[kq+3][r]=v.w;
            }
            __syncthreads();
#pragma unroll
            for (int k = 0; k < BK; ++k) {
                float4 a4 = *reinterpret_cast<const float4*>(&xs[k][ty * 4]);
                float4 b0 = *reinterpret_cast<const float4*>(&es[k][tx * 8]);
                float4 b1 = *reinterpret_cast<const float4*>(&es[k][tx * 8 + 4]);
                float a[4] = {a4.x, a4.y, a4.z, a4.w};
                float b[8] = {b0.x, b0.y, b0.z, b0.w, b1.x, b1.y, b1.z, b1.w};
#pragma unroll
                for (int i = 0; i < 4; ++i)
#pragma unroll
                    for (int j = 0; j < 8; ++j)
                        acc[i][j] = fmaf(a[i], b[j], acc[i][j]);
            }
            __syncthreads();
        }
#pragma unroll
        for (int i = 0; i < 4; ++i) {
            float v = -3.0e38f; int vi = 0;
#pragma unroll
            for (int j = 0; j < 8; ++j) {
                int col = ct + tx * 8 + j;
                float s = acc[i][j] * inv_norm[col];
                if (s > v) { v = s; vi = col; }
            }
#pragma unroll
            for (int off = 1; off < 16; off <<= 1) {
                float ov = __shfl_xor(v, off, 16);
                int   oi = __shfl_xor(vi, off, 16);
                if (ov > v || (ov == v && oi < vi)) { v = ov; vi = oi; }
            }
            if (v > bestv[i] || (v == bestv[i] && vi < besti[i])) {
                bestv[i] = v; besti[i] = vi;
            }
        }
    }
    if (tx == 0) {
#pragma unroll
        for (int i = 0; i < 4; ++i) ind[row0 + ty * 4 + i] = besti[i];
    }
}

// =========================================================================
extern "C" void kernel_launch(void* const* d_in, const int* in_sizes, int n_in,
                              void* d_out, int out_size, void* d_ws, size_t ws_size,
                              hipStream_t stream) {
    const float* x     = (const float*)d_in[0];
    const float* embed = (const float*)d_in[1];
    const int M = in_sizes[0] / D;   // 32768
    const int C = in_sizes[1] / D;   // 8192

    float* out_q = (float*)d_out;
    float* out_i = (float*)d_out + (size_t)M * D;

    // workspace layout for the MFMA path
    size_t X2_off   = 0;
    size_t X2_sz    = (size_t)M * K2 * 2;
    size_t E2_off   = X2_off + X2_sz;
    size_t E2_sz    = (size_t)C * K2 * 2;
    size_t inv_off  = E2_off + E2_sz;
    size_t inv_sz   = (size_t)C * 4;
    size_t part_off = inv_off + inv_sz;
    size_t part_sz  = (size_t)M * 4 * 16;
    size_t ind_off  = part_off + part_sz;
    size_t ind_sz   = (size_t)M * 4;
    size_t fbc_off  = ind_off + ind_sz;
    size_t fbr_off  = fbc_off + 16;
    size_t fbr_sz   = (size_t)M * 4;
    size_t best_off = fbr_off + fbr_sz;
    size_t total    = best_off + (size_t)M * 8;

    if (ws_size >= total && M == MROWS && C == CCOLS) {
        char* ws = (char*)d_ws;
        unsigned short* X2 = (unsigned short*)(ws + X2_off);
        unsigned short* E2 = (unsigned short*)(ws + E2_off);
        float* inv_norm    = (float*)(ws + inv_off);
        float4* partials   = (float4*)(ws + part_off);
        int* ind           = (int*)(ws + ind_off);
        int* fb_count      = (int*)(ws + fbc_off);
        int* fb_rows       = (int*)(ws + fbr_off);
        unsigned long long* best = (unsigned long long*)(ws + best_off);

        hipMemsetAsync(fb_count, 0, 16, stream);
        prep_embed_kernel<<<C, 64, 0, stream>>>(embed, E2, inv_norm);
        prep_x_kernel<<<M, 64, 0, stream>>>(x, X2);
        gemm_topk3_kernel<<<(M / 256) * NSPLIT, 640, 0, stream>>>(X2, E2, partials);
        combine_kernel<<<M / 256, 256, 0, stream>>>(partials, ind, fb_count, fb_rows, best);
        fallback_kernel<<<C / 16, 256, 0, stream>>>(x, embed, inv_norm, fb_count, fb_rows, best);
        fbwrite_kernel<<<1, 256, 0, stream>>>(fb_count, fb_rows, best, ind);
        gather_kernel<<<M, 128, 0, stream>>>(embed, ind, out_q, out_i);
    } else {
        float* inv_norm = (float*)d_ws;
        int*   ind      = (int*)d_ws + C;
        norm_kernel<<<C, 64, 0, stream>>>(embed, inv_norm);
        gemm_argmax_kernel<<<M / BM, 256, 0, stream>>>(x, embed, inv_norm, ind, C);
        gather_kernel<<<M, 128, 0, stream>>>(embed, ind, out_q, out_i);
    }
}

// Round 8
// 1316.001 us; speedup vs baseline: 4.4936x; 4.4936x over previous
//
#include <hip/hip_runtime.h>
#include <math.h>

#define D 512
#define MROWS 32768
#define CCOLS 8192
#define K2 1536
#define NT 24            // K-tiles of 64
#define NSPLIT 2
#define CT_PER_SPLIT 16  // 4096 cols / 256
#define SUBT_PER_CTI (NT * 2)                 // 48 subtiles (k=32) per col-tile
#define SUBT_TOTAL (CT_PER_SPLIT * SUBT_PER_CTI)  // 768
#define TAU 2.0e-4f

typedef __attribute__((ext_vector_type(8))) short short8v;
typedef __attribute__((ext_vector_type(4))) float f32x4;

__device__ __forceinline__ unsigned short f2bf_rne(float f) {
    unsigned u = __float_as_uint(f);
    unsigned r = ((u >> 16) & 1u) + 0x7FFFu;
    return (unsigned short)((u + r) >> 16);
}
__device__ __forceinline__ float bf2f(unsigned short h) {
    return __uint_as_float(((unsigned)h) << 16);
}

__device__ __forceinline__ void gload_lds16(const void* gsrc, void* ldst) {
    __builtin_amdgcn_global_load_lds(
        (const __attribute__((address_space(1))) unsigned int*)gsrc,
        (__attribute__((address_space(3))) unsigned int*)ldst, 16, 0, 0);
}

// ---------- prep: codebook -> inv_norm + E2 = [hi(e_n) | lo(e_n) | hi(e_n)] ----------
__global__ __launch_bounds__(64) void prep_embed_kernel(
    const float* __restrict__ embed, unsigned short* __restrict__ E2,
    float* __restrict__ inv_norm) {
    int cb = blockIdx.x, lane = threadIdx.x;
    const float4* r4 = reinterpret_cast<const float4*>(embed + (size_t)cb * D);
    float4 a = r4[lane], b = r4[lane + 64];
    float ss = a.x*a.x + a.y*a.y + a.z*a.z + a.w*a.w
             + b.x*b.x + b.y*b.y + b.z*b.z + b.w*b.w;
#pragma unroll
    for (int off = 32; off > 0; off >>= 1) ss += __shfl_xor(ss, off);
    float inv = 1.0f / fmaxf(sqrtf(ss), 1e-12f);
    if (lane == 0) inv_norm[cb] = inv;
    float ea[4] = {a.x*inv, a.y*inv, a.z*inv, a.w*inv};
    float eb[4] = {b.x*inv, b.y*inv, b.z*inv, b.w*inv};
    ushort4 ha, la, hb, lb;
    { for (int j=0;j<4;++j) (&ha.x)[j] = f2bf_rne(ea[j]); }
    { for (int j=0;j<4;++j) (&la.x)[j] = f2bf_rne(ea[j] - bf2f((&ha.x)[j])); }
    { for (int j=0;j<4;++j) (&hb.x)[j] = f2bf_rne(eb[j]); }
    { for (int j=0;j<4;++j) (&lb.x)[j] = f2bf_rne(eb[j] - bf2f((&hb.x)[j])); }
    unsigned short* row = E2 + (size_t)cb * K2;
    int k = lane * 4;
    *(ushort4*)&row[k]          = ha;  // hi  at [0,512)
    *(ushort4*)&row[256 + k]    = hb;
    *(ushort4*)&row[512 + k]    = la;  // lo  at [512,1024)
    *(ushort4*)&row[768 + k]    = lb;
    *(ushort4*)&row[1024 + k]   = ha;  // hi  at [1024,1536)
    *(ushort4*)&row[1280 + k]   = hb;
}

// ---------- prep: x -> X2 = [hi(x) | hi(x) | lo(x)] ----------
__global__ __launch_bounds__(64) void prep_x_kernel(
    const float* __restrict__ x, unsigned short* __restrict__ X2) {
    int rb = blockIdx.x, lane = threadIdx.x;
    const float4* r4 = reinterpret_cast<const float4*>(x + (size_t)rb * D);
    float4 a = r4[lane], b = r4[lane + 64];
    float ea[4] = {a.x, a.y, a.z, a.w};
    float eb[4] = {b.x, b.y, b.z, b.w};
    ushort4 ha, la, hb, lb;
    { for (int j=0;j<4;++j) (&ha.x)[j] = f2bf_rne(ea[j]); }
    { for (int j=0;j<4;++j) (&la.x)[j] = f2bf_rne(ea[j] - bf2f((&ha.x)[j])); }
    { for (int j=0;j<4;++j) (&hb.x)[j] = f2bf_rne(eb[j]); }
    { for (int j=0;j<4;++j) (&lb.x)[j] = f2bf_rne(eb[j] - bf2f((&hb.x)[j])); }
    unsigned short* row = X2 + (size_t)rb * K2;
    int k = lane * 4;
    *(ushort4*)&row[k]        = ha;   // hi
    *(ushort4*)&row[256 + k]  = hb;
    *(ushort4*)&row[512 + k]  = ha;   // hi again
    *(ushort4*)&row[768 + k]  = hb;
    *(ushort4*)&row[1024 + k] = la;   // lo
    *(ushort4*)&row[1280 + k] = lb;
}

// ---------- 256x256-tile bf16 GEMM + per-row top-2, subtile-ring pipeline ----------
// 512 threads = 8 waves (4M x 2N). Per-wave output 64 rows x 128 cols.
// K split into k=32 subtiles; 4-slot LDS ring (A 16KB + B 16KB per slot).
// Phase S: vmcnt(8) [slot data S landed] -> stage S+3 -> barrier ->
// ds_read 8 -> lgkm(0) -> 16 MFMA -> ds_read 4 -> lgkm(0) -> 16 MFMA -> barrier.
// Loads always >=8 in flight; each subtile gets ~3 phases of latency cover.
__global__ __launch_bounds__(512, 2) void gemm_topk4_kernel(
    const unsigned short* __restrict__ X2, const unsigned short* __restrict__ E2,
    float4* __restrict__ partials) {
    __shared__ __align__(16) unsigned short AsR[4][256 * 32];
    __shared__ __align__(16) unsigned short BsR[4][256 * 32];
    __shared__ float smv1[256], smv2[256];
    __shared__ int   smi[256];

    const int tid  = threadIdx.x;
    const int lane = tid & 63;
    const int w    = tid >> 6;          // 0..7
    const int wm   = w >> 1;            // 0..3 (row group of 64)
    const int wn   = w & 1;             // 0..1 (col group of 128)
    const int c    = lane & 15;
    const int qh   = lane >> 4;         // k-granule 0..3

    // bijective XCD-contiguous mapping: XCD x owns logical [x*32, x*32+32)
    const int bid     = blockIdx.x;
    const int logical = (bid & 7) * 32 + (bid >> 3);
    const int split   = logical >> 7;        // 0..1
    const int rowtile = logical & 127;       // 0..127
    const size_t grow0 = (size_t)rowtile * 256;
    const int col0     = split * (CT_PER_SPLIT * 256);

    float v1[16], v2[16]; int i1[16];
#pragma unroll
    for (int s = 0; s < 16; ++s) { v1[s] = -3.0e38f; v2[s] = -3.0e38f; i1[s] = 0; }

    // stage subtile S (global index): 4 gload_lds/thread into ring slot S&3.
    // Linear LDS dst granule G; source granule pre-swizzled (G&3)^(row&3)
    // (both-sides involution with the consumer read swizzle).
#define STAGE_SUBT(S)                                                         \
    { int cti_ = (S) / SUBT_PER_CTI;                                          \
      int rem_ = (S) - cti_ * SUBT_PER_CTI;                                   \
      int kb_  = (rem_ >> 1) * 64 + (rem_ & 1) * 32;                          \
      int ct_  = col0 + cti_ * 256;                                           \
      int sl_  = (S) & 3;                                                     \
      _Pragma("unroll")                                                       \
      for (int i_ = 0; i_ < 2; ++i_) {                                        \
          int G_ = tid + i_ * 512; int row_ = G_ >> 2;                        \
          int gs_ = (G_ & 3) ^ (row_ & 3);                                    \
          gload_lds16(X2 + (grow0 + row_) * (size_t)K2 + kb_ + gs_ * 8,       \
                      &AsR[sl_][G_ * 8]);                                     \
      }                                                                       \
      _Pragma("unroll")                                                       \
      for (int i_ = 0; i_ < 2; ++i_) {                                        \
          int G_ = tid + i_ * 512; int row_ = G_ >> 2;                        \
          int gs_ = (G_ & 3) ^ (row_ & 3);                                    \
          gload_lds16(E2 + (size_t)(ct_ + row_) * K2 + kb_ + gs_ * 8,         \
                      &BsR[sl_][G_ * 8]);                                     \
      } }

    // prologue: stage subtiles 0,1,2 (12 loads in flight)
    STAGE_SUBT(0);
    STAGE_SUBT(1);
    STAGE_SUBT(2);

    int sgi = 0;
    for (int cti = 0; cti < CT_PER_SPLIT; ++cti) {
        const int ct0 = col0 + cti * 256;
        f32x4 acc[4][8];
#pragma unroll
        for (int m = 0; m < 4; ++m)
#pragma unroll
            for (int n = 0; n < 8; ++n) acc[m][n] = (f32x4){0.f, 0.f, 0.f, 0.f};

#pragma unroll 4
        for (int s = 0; s < SUBT_PER_CTI; ++s, ++sgi) {
            const int slot = sgi & 3;
            // counted wait: own share of subtile sgi has landed
            if (sgi < SUBT_TOTAL - 2) {
                asm volatile("s_waitcnt vmcnt(8)" ::: "memory");
            } else if (sgi == SUBT_TOTAL - 2) {
                asm volatile("s_waitcnt vmcnt(4)" ::: "memory");
            } else {
                asm volatile("s_waitcnt vmcnt(0)" ::: "memory");
            }
            // stage subtile sgi+3 into slot (sgi+3)&3 = (sgi-1)&3
            // (freed by previous phase's post-lgkm barrier)
            if (sgi + 3 < SUBT_TOTAL) { STAGE_SUBT(sgi + 3); }
            __builtin_amdgcn_s_barrier();          // all waves' subtile sgi landed
            __builtin_amdgcn_sched_barrier(0);

            short8v af[4], bf[4];
#pragma unroll
            for (int m = 0; m < 4; ++m) {
                int row = wm * 64 + m * 16 + c;
                int g   = qh ^ (row & 3);
                af[m] = *(const short8v*)&AsR[slot][row * 32 + g * 8];
            }
#pragma unroll
            for (int n = 0; n < 4; ++n) {
                int rb = wn * 128 + n * 16 + c;
                int g  = qh ^ (rb & 3);
                bf[n] = *(const short8v*)&BsR[slot][rb * 32 + g * 8];
            }
            asm volatile("s_waitcnt lgkmcnt(0)" ::: "memory");
            __builtin_amdgcn_sched_barrier(0);
            __builtin_amdgcn_s_setprio(1);
#pragma unroll
            for (int m = 0; m < 4; ++m)
#pragma unroll
                for (int n = 0; n < 4; ++n)
                    acc[m][n] = __builtin_amdgcn_mfma_f32_16x16x32_bf16(
                        af[m], bf[n], acc[m][n], 0, 0, 0);
            __builtin_amdgcn_s_setprio(0);
#pragma unroll
            for (int n = 0; n < 4; ++n) {
                int rb = wn * 128 + (n + 4) * 16 + c;
                int g  = qh ^ (rb & 3);
                bf[n] = *(const short8v*)&BsR[slot][rb * 32 + g * 8];
            }
            asm volatile("s_waitcnt lgkmcnt(0)" ::: "memory");
            __builtin_amdgcn_sched_barrier(0);
            __builtin_amdgcn_s_setprio(1);
#pragma unroll
            for (int m = 0; m < 4; ++m)
#pragma unroll
                for (int n = 0; n < 4; ++n)
                    acc[m][n + 4] = __builtin_amdgcn_mfma_f32_16x16x32_bf16(
                        af[m], bf[n], acc[m][n + 4], 0, 0, 0);
            __builtin_amdgcn_s_setprio(0);
            __builtin_amdgcn_sched_barrier(0);
            asm volatile("" ::: "memory");
            __builtin_amdgcn_s_barrier();          // reads of this slot done
        }

        // fold this 256-col tile into running per-lane top-2
#pragma unroll
        for (int m = 0; m < 4; ++m)
#pragma unroll
            for (int n = 0; n < 8; ++n) {
                int col = ct0 + wn * 128 + n * 16 + c;
#pragma unroll
                for (int r = 0; r < 4; ++r) {
                    float sv = acc[m][n][r];
                    int slot2 = m * 4 + r;
                    if (sv > v1[slot2]) { v2[slot2] = v1[slot2]; v1[slot2] = sv; i1[slot2] = col; }
                    else if (sv > v2[slot2]) v2[slot2] = sv;
                }
            }
    }
#undef STAGE_SUBT

    // cross-lane merge over the 16 col-lanes (rows fixed per (qh,slot))
#pragma unroll
    for (int s = 0; s < 16; ++s) {
        float a1 = v1[s], a2 = v2[s]; int ai = i1[s];
#pragma unroll
        for (int off = 1; off < 16; off <<= 1) {
            float o1 = __shfl_xor(a1, off);
            float o2 = __shfl_xor(a2, off);
            int   oi = __shfl_xor(ai, off);
            if (o1 > a1 || (o1 == a1 && oi < ai)) {
                a2 = fmaxf(a1, o2); a1 = o1; ai = oi;
            } else {
                a2 = fmaxf(a2, o1);   // tie with larger idx -> gap 0 -> fallback
            }
        }
        v1[s] = a1; v2[s] = a2; i1[s] = ai;
    }
    // merge the two wn-waves (same rows, different col halves) via LDS
    if (c == 0 && wn == 1) {
#pragma unroll
        for (int s = 0; s < 16; ++s) {
            int li = wm * 64 + qh * 16 + s;
            smv1[li] = v1[s]; smv2[li] = v2[s]; smi[li] = i1[s];
        }
    }
    __syncthreads();
    if (c == 0 && wn == 0) {
#pragma unroll
        for (int s = 0; s < 16; ++s) {
            int li = wm * 64 + qh * 16 + s;
            float o1 = smv1[li], o2 = smv2[li]; int oi = smi[li];
            if (o1 > v1[s] || (o1 == v1[s] && oi < i1[s])) {
                v2[s] = fmaxf(v1[s], o2); v1[s] = o1; i1[s] = oi;
            } else {
                v2[s] = fmaxf(v2[s], o1);
            }
            int row = (int)grow0 + wm * 64 + (s >> 2) * 16 + qh * 4 + (s & 3);
            partials[(size_t)row * 4 + split] =
                make_float4(v1[s], v2[s], __int_as_float(i1[s]), 0.f);
        }
    }
}

// ---------- combine split-partials, gap test, enqueue fallback ----------
__global__ __launch_bounds__(256) void combine_kernel(
    const float4* __restrict__ partials, int* __restrict__ ind,
    int* __restrict__ fb_count, int* __restrict__ fb_rows,
    unsigned long long* __restrict__ best) {
    int row = blockIdx.x * 256 + threadIdx.x;
    if (row >= MROWS) return;
    float g1 = -3.0e38f, g2 = -3.0e38f; int gi = 0;
#pragma unroll
    for (int s = 0; s < NSPLIT; ++s) {
        float4 p = partials[(size_t)row * 4 + s];
        if (p.x > g1 || (p.x == g1 && __float_as_int(p.z) < gi)) {
            g2 = fmaxf(g1, p.y); g1 = p.x; gi = __float_as_int(p.z);
        } else {
            g2 = fmaxf(g2, p.x);
        }
    }
    ind[row] = gi;
    if (g1 - g2 <= TAU) {
        int k = atomicAdd(fb_count, 1);
        fb_rows[k] = row;
        best[row] = 0ull;
    }
}

// ---------- exact f32 rescore for flagged rows ----------
__global__ __launch_bounds__(256) void fallback_kernel(
    const float* __restrict__ x, const float* __restrict__ embed,
    const float* __restrict__ inv_norm, const int* __restrict__ fb_count,
    const int* __restrict__ fb_rows, unsigned long long* __restrict__ best) {
    __shared__ float es[16][D];
    __shared__ float xs[D];
    const int t = threadIdx.x;
    const int c0 = blockIdx.x * 16;
    for (int i = t; i < 16 * 128; i += 256) {
        int col = i >> 7, f4 = i & 127;
        *(float4*)&es[col][f4 * 4] =
            *(const float4*)&embed[(size_t)(c0 + col) * D + f4 * 4];
    }
    const int nfb = *fb_count;
    const int col = t >> 4, s = t & 15;
    for (int ri = 0; ri < nfb; ++ri) {
        int row = fb_rows[ri];
        __syncthreads();
        if (t < 128)
            *(float4*)&xs[t * 4] = *(const float4*)&x[(size_t)row * D + t * 4];
        __syncthreads();
        float dot = 0.f;
        const float* ep = &es[col][s * 32];
        const float* xp = &xs[s * 32];
#pragma unroll
        for (int k = 0; k < 8; ++k) {
            float4 a = *(const float4*)&xp[k * 4];
            float4 b = *(const float4*)&ep[k * 4];
            dot = fmaf(a.x, b.x, fmaf(a.y, b.y, fmaf(a.z, b.z, fmaf(a.w, b.w, dot))));
        }
        dot += __shfl_xor(dot, 1); dot += __shfl_xor(dot, 2);
        dot += __shfl_xor(dot, 4); dot += __shfl_xor(dot, 8);
        if (s == 0) {
            float score = dot * inv_norm[c0 + col];
            unsigned fb = __float_as_uint(score);
            fb = (fb & 0x80000000u) ? ~fb : (fb | 0x80000000u);
            unsigned long long key = ((unsigned long long)fb << 32) |
                (unsigned long long)(0xFFFFFFFFu - (unsigned)(c0 + col));
            atomicMax(best + row, key);
        }
    }
}

__global__ void fbwrite_kernel(const int* __restrict__ fb_count,
                               const int* __restrict__ fb_rows,
                               const unsigned long long* __restrict__ best,
                               int* __restrict__ ind) {
    int n = *fb_count;
    for (int i = threadIdx.x; i < n; i += 256) {
        int row = fb_rows[i];
        unsigned long long k = best[row];
        ind[row] = (int)(0xFFFFFFFFu - (unsigned)(k & 0xFFFFFFFFull));
    }
}

// ---------- gather ----------
__global__ __launch_bounds__(128) void gather_kernel(
    const float* __restrict__ embed, const int* __restrict__ ind,
    float* __restrict__ out_q, float* __restrict__ out_i) {
    int row = blockIdx.x;
    int t = threadIdx.x;
    int idx = ind[row];
    const float4* src = reinterpret_cast<const float4*>(embed + (size_t)idx * D);
    float4* dst = reinterpret_cast<float4*>(out_q + (size_t)row * D);
    dst[t] = src[t];
    if (t == 0) out_i[row] = (float)idx;
}

// ================= legacy f32 path (used if ws too small) =================
#define BM 64
#define BN 128
#define BK 32
#define LDX (BM + 4)
#define LDE (BN + 4)

__global__ __launch_bounds__(64) void norm_kernel(const float* __restrict__ embed,
                                                  float* __restrict__ inv_norm) {
    int cb = blockIdx.x, lane = threadIdx.x;
    const float4* r4 = reinterpret_cast<const float4*>(embed + (size_t)cb * D);
    float4 a = r4[lane], b = r4[lane + 64];
    float s = a.x*a.x + a.y*a.y + a.z*a.z + a.w*a.w
            + b.x*b.x + b.y*b.y + b.z*b.z + b.w*b.w;
#pragma unroll
    for (int off = 32; off > 0; off >>= 1) s += __shfl_xor(s, off);
    if (lane == 0) inv_norm[cb] = 1.0f / fmaxf(sqrtf(s), 1e-12f);
}

__global__ __launch_bounds__(256) void gemm_argmax_kernel(
    const float* __restrict__ x, const float* __restrict__ embed,
    const float* __restrict__ inv_norm, int* __restrict__ ind, int C) {
    __shared__ float xs[BK][LDX];
    __shared__ float es[BK][LDE];
    const int tid = threadIdx.x;
    const int tx = tid & 15;
    const int ty = tid >> 4;
    const int row0 = blockIdx.x * BM;
    float bestv[4]; int besti[4];
#pragma unroll
    for (int i = 0; i < 4; ++i) { bestv[i] = -3.0e38f; besti[i] = 0; }
    for (int ct = 0; ct < C; ct += BN) {
        float acc[4][8];
#pragma unroll
        for (int i = 0; i < 4; ++i)
#pragma unroll
            for (int j = 0; j < 8; ++j) acc[i][j] = 0.0f;
        for (int kt = 0; kt < D; kt += BK) {
#pragma unroll
            for (int i = 0; i < 2; ++i) {
                int f = tid + i * 256;
                int r = f >> 3, kq = (f & 7) << 2;
                float4 v = *reinterpret_cast<const float4*>(
                    x + (size_t)(row0 + r) * D + kt + kq);
                xs[kq+0][r]=v.x; xs[kq+1][r]=v.y; xs[kq+2][r]=v.z; xs[kq+3][r]=v.w;
            }
#pragma unroll
            for (int i = 0; i < 4; ++i) {
                int f = tid + i * 256;
                int r = f >> 3, kq = (f & 7) << 2;
                float4 v = *reinterpret_cast<const float4*>(
                    embed + (size_t)(ct + r) * D + kt + kq);
                es[kq+0][r]=v.x; es[kq+1][r]=v.y; es[kq+2][r]=v.z; es[kq+3][r]=v.w;
            }
            __syncthreads();
#pragma unroll
            for (int k = 0; k < BK; ++k) {
                float4 a4 = *reinterpret_cast<const float4*>(&xs[k][ty * 4]);
                float4 b0 = *reinterpret_cast<const float4*>(&es[k][tx * 8]);
                float4 b1 = *reinterpret_cast<const float4*>(&es[k][tx * 8 + 4]);
                float a[4] = {a4.x, a4.y, a4.z, a4.w};
                float b[8] = {b0.x, b0.y, b0.z, b0.w, b1.x, b1.y, b1.z, b1.w};
#pragma unroll
                for (int i = 0; i < 4; ++i)
#pragma unroll
                    for (int j = 0; j < 8; ++j)
                        acc[i][j] = fmaf(a[i], b[j], acc[i][j]);
            }
            __syncthreads();
        }
#pragma unroll
        for (int i = 0; i < 4; ++i) {
            float v = -3.0e38f; int vi = 0;
#pragma unroll
            for (int j = 0; j < 8; ++j) {
                int col = ct + tx * 8 + j;
                float s = acc[i][j] * inv_norm[col];
                if (s > v) { v = s; vi = col; }
            }
#pragma unroll
            for (int off = 1; off < 16; off <<= 1) {
                float ov = __shfl_xor(v, off, 16);
                int   oi = __shfl_xor(vi, off, 16);
                if (ov > v || (ov == v && oi < vi)) { v = ov; vi = oi; }
            }
            if (v > bestv[i] || (v == bestv[i] && vi < besti[i])) {
                bestv[i] = v; besti[i] = vi;
            }
        }
    }
    if (tx == 0) {
#pragma unroll
        for (int i = 0; i < 4; ++i) ind[row0 + ty * 4 + i] = besti[i];
    }
}

// =========================================================================
extern "C" void kernel_launch(void* const* d_in, const int* in_sizes, int n_in,
                              void* d_out, int out_size, void* d_ws, size_t ws_size,
                              hipStream_t stream) {
    const float* x     = (const float*)d_in[0];
    const float* embed = (const float*)d_in[1];
    const int M = in_sizes[0] / D;   // 32768
    const int C = in_sizes[1] / D;   // 8192

    float* out_q = (float*)d_out;
    float* out_i = (float*)d_out + (size_t)M * D;

    // workspace layout for the MFMA path
    size_t X2_off   = 0;
    size_t X2_sz    = (size_t)M * K2 * 2;
    size_t E2_off   = X2_off + X2_sz;
    size_t E2_sz    = (size_t)C * K2 * 2;
    size_t inv_off  = E2_off + E2_sz;
    size_t inv_sz   = (size_t)C * 4;
    size_t part_off = inv_off + inv_sz;
    size_t part_sz  = (size_t)M * 4 * 16;
    size_t ind_off  = part_off + part_sz;
    size_t ind_sz   = (size_t)M * 4;
    size_t fbc_off  = ind_off + ind_sz;
    size_t fbr_off  = fbc_off + 16;
    size_t fbr_sz   = (size_t)M * 4;
    size_t best_off = fbr_off + fbr_sz;
    size_t total    = best_off + (size_t)M * 8;

    if (ws_size >= total && M == MROWS && C == CCOLS) {
        char* ws = (char*)d_ws;
        unsigned short* X2 = (unsigned short*)(ws + X2_off);
        unsigned short* E2 = (unsigned short*)(ws + E2_off);
        float* inv_norm    = (float*)(ws + inv_off);
        float4* partials   = (float4*)(ws + part_off);
        int* ind           = (int*)(ws + ind_off);
        int* fb_count      = (int*)(ws + fbc_off);
        int* fb_rows       = (int*)(ws + fbr_off);
        unsigned long long* best = (unsigned long long*)(ws + best_off);

        hipMemsetAsync(fb_count, 0, 16, stream);
        prep_embed_kernel<<<C, 64, 0, stream>>>(embed, E2, inv_norm);
        prep_x_kernel<<<M, 64, 0, stream>>>(x, X2);
        gemm_topk4_kernel<<<(M / 256) * NSPLIT, 512, 0, stream>>>(X2, E2, partials);
        combine_kernel<<<M / 256, 256, 0, stream>>>(partials, ind, fb_count, fb_rows, best);
        fallback_kernel<<<C / 16, 256, 0, stream>>>(x, embed, inv_norm, fb_count, fb_rows, best);
        fbwrite_kernel<<<1, 256, 0, stream>>>(fb_count, fb_rows, best, ind);
        gather_kernel<<<M, 128, 0, stream>>>(embed, ind, out_q, out_i);
    } else {
        float* inv_norm = (float*)d_ws;
        int*   ind      = (int*)d_ws + C;
        norm_kernel<<<C, 64, 0, stream>>>(embed, inv_norm);
        gemm_argmax_kernel<<<M / BM, 256, 0, stream>>>(x, embed, inv_norm, ind, C);
        gather_kernel<<<M, 128, 0, stream>>>(embed, ind, out_q, out_i);
    }
}

// Round 9
// 1191.852 us; speedup vs baseline: 4.9617x; 1.1042x over previous
//
#include <hip/hip_runtime.h>
#include <math.h>

#define D 512
#define MROWS 32768
#define CCOLS 8192
#define K2 1536
#define NT 24            // K-tiles of 64
#define NSPLIT 2
#define CT_PER_SPLIT 16  // 4096 cols / 256
#define SUBT_PER_CTI (NT * 2)                 // 48 subtiles (k=32) per col-tile
#define SUBT_TOTAL (CT_PER_SPLIT * SUBT_PER_CTI)  // 768
#define TAU 2.0e-4f

typedef __attribute__((ext_vector_type(8))) short short8v;
typedef __attribute__((ext_vector_type(4))) float f32x4;

__device__ __forceinline__ unsigned short f2bf_rne(float f) {
    unsigned u = __float_as_uint(f);
    unsigned r = ((u >> 16) & 1u) + 0x7FFFu;
    return (unsigned short)((u + r) >> 16);
}
__device__ __forceinline__ float bf2f(unsigned short h) {
    return __uint_as_float(((unsigned)h) << 16);
}

__device__ __forceinline__ void gload_lds16(const void* gsrc, void* ldst) {
    __builtin_amdgcn_global_load_lds(
        (const __attribute__((address_space(1))) unsigned int*)gsrc,
        (__attribute__((address_space(3))) unsigned int*)ldst, 16, 0, 0);
}

// ---------- prep: codebook -> inv_norm + E2 = [hi(e_n) | lo(e_n) | hi(e_n)] ----------
__global__ __launch_bounds__(64) void prep_embed_kernel(
    const float* __restrict__ embed, unsigned short* __restrict__ E2,
    float* __restrict__ inv_norm) {
    int cb = blockIdx.x, lane = threadIdx.x;
    const float4* r4 = reinterpret_cast<const float4*>(embed + (size_t)cb * D);
    float4 a = r4[lane], b = r4[lane + 64];
    float ss = a.x*a.x + a.y*a.y + a.z*a.z + a.w*a.w
             + b.x*b.x + b.y*b.y + b.z*b.z + b.w*b.w;
#pragma unroll
    for (int off = 32; off > 0; off >>= 1) ss += __shfl_xor(ss, off);
    float inv = 1.0f / fmaxf(sqrtf(ss), 1e-12f);
    if (lane == 0) inv_norm[cb] = inv;
    float ea[4] = {a.x*inv, a.y*inv, a.z*inv, a.w*inv};
    float eb[4] = {b.x*inv, b.y*inv, b.z*inv, b.w*inv};
    ushort4 ha, la, hb, lb;
    { for (int j=0;j<4;++j) (&ha.x)[j] = f2bf_rne(ea[j]); }
    { for (int j=0;j<4;++j) (&la.x)[j] = f2bf_rne(ea[j] - bf2f((&ha.x)[j])); }
    { for (int j=0;j<4;++j) (&hb.x)[j] = f2bf_rne(eb[j]); }
    { for (int j=0;j<4;++j) (&lb.x)[j] = f2bf_rne(eb[j] - bf2f((&hb.x)[j])); }
    unsigned short* row = E2 + (size_t)cb * K2;
    int k = lane * 4;
    *(ushort4*)&row[k]          = ha;  // hi  at [0,512)
    *(ushort4*)&row[256 + k]    = hb;
    *(ushort4*)&row[512 + k]    = la;  // lo  at [512,1024)
    *(ushort4*)&row[768 + k]    = lb;
    *(ushort4*)&row[1024 + k]   = ha;  // hi  at [1024,1536)
    *(ushort4*)&row[1280 + k]   = hb;
}

// ---------- prep: x -> X2 = [hi(x) | hi(x) | lo(x)] ----------
__global__ __launch_bounds__(64) void prep_x_kernel(
    const float* __restrict__ x, unsigned short* __restrict__ X2) {
    int rb = blockIdx.x, lane = threadIdx.x;
    const float4* r4 = reinterpret_cast<const float4*>(x + (size_t)rb * D);
    float4 a = r4[lane], b = r4[lane + 64];
    float ea[4] = {a.x, a.y, a.z, a.w};
    float eb[4] = {b.x, b.y, b.z, b.w};
    ushort4 ha, la, hb, lb;
    { for (int j=0;j<4;++j) (&ha.x)[j] = f2bf_rne(ea[j]); }
    { for (int j=0;j<4;++j) (&la.x)[j] = f2bf_rne(ea[j] - bf2f((&ha.x)[j])); }
    { for (int j=0;j<4;++j) (&hb.x)[j] = f2bf_rne(eb[j]); }
    { for (int j=0;j<4;++j) (&lb.x)[j] = f2bf_rne(eb[j] - bf2f((&hb.x)[j])); }
    unsigned short* row = X2 + (size_t)rb * K2;
    int k = lane * 4;
    *(ushort4*)&row[k]        = ha;   // hi
    *(ushort4*)&row[256 + k]  = hb;
    *(ushort4*)&row[512 + k]  = ha;   // hi again
    *(ushort4*)&row[768 + k]  = hb;
    *(ushort4*)&row[1024 + k] = la;   // lo
    *(ushort4*)&row[1280 + k] = lb;
}

// ---------- 256x256-tile bf16 GEMM + per-row top-2, subtile-ring pipeline ----------
// 512 threads = 8 waves (4M x 2N). Per-wave output 64 rows x 128 cols.
// K split into k=32 subtiles; 4-slot LDS ring (A 16KB + B 16KB per slot).
// Granule swizzle XOR (row>>1)&3: bank-quad = 4*(row&1) + qh^((row>>1)&3)
// walks all 8 quads over 8 rows -> conflict-free ds_read_b128 (2 lanes/quad
// per quarter-wave). Same involution applied on the staging SOURCE (rule:
// both-sides-or-neither).
__global__ __launch_bounds__(512, 2) void gemm_topk4_kernel(
    const unsigned short* __restrict__ X2, const unsigned short* __restrict__ E2,
    float4* __restrict__ partials) {
    __shared__ __align__(16) unsigned short AsR[4][256 * 32];
    __shared__ __align__(16) unsigned short BsR[4][256 * 32];
    __shared__ float smv1[256], smv2[256];
    __shared__ int   smi[256];

    const int tid  = threadIdx.x;
    const int lane = tid & 63;
    const int w    = tid >> 6;          // 0..7
    const int wm   = w >> 1;            // 0..3 (row group of 64)
    const int wn   = w & 1;             // 0..1 (col group of 128)
    const int c    = lane & 15;
    const int qh   = lane >> 4;         // k-granule 0..3

    // bijective XCD-contiguous mapping: XCD x owns logical [x*32, x*32+32)
    const int bid     = blockIdx.x;
    const int logical = (bid & 7) * 32 + (bid >> 3);
    const int split   = logical >> 7;        // 0..1
    const int rowtile = logical & 127;       // 0..127
    const size_t grow0 = (size_t)rowtile * 256;
    const int col0     = split * (CT_PER_SPLIT * 256);

    float v1[16], v2[16]; int i1[16];
#pragma unroll
    for (int s = 0; s < 16; ++s) { v1[s] = -3.0e38f; v2[s] = -3.0e38f; i1[s] = 0; }

    // stage subtile S (global index): 4 gload_lds/thread into ring slot S&3.
    // Linear LDS dst granule G; source granule pre-swizzled (G&3)^((row>>1)&3)
    // (both-sides involution with the consumer read swizzle).
#define STAGE_SUBT(S)                                                         \
    { int cti_ = (S) / SUBT_PER_CTI;                                          \
      int rem_ = (S) - cti_ * SUBT_PER_CTI;                                   \
      int kb_  = (rem_ >> 1) * 64 + (rem_ & 1) * 32;                          \
      int ct_  = col0 + cti_ * 256;                                           \
      int sl_  = (S) & 3;                                                     \
      _Pragma("unroll")                                                       \
      for (int i_ = 0; i_ < 2; ++i_) {                                        \
          int G_ = tid + i_ * 512; int row_ = G_ >> 2;                        \
          int gs_ = (G_ & 3) ^ ((row_ >> 1) & 3);                             \
          gload_lds16(X2 + (grow0 + row_) * (size_t)K2 + kb_ + gs_ * 8,       \
                      &AsR[sl_][G_ * 8]);                                     \
      }                                                                       \
      _Pragma("unroll")                                                       \
      for (int i_ = 0; i_ < 2; ++i_) {                                        \
          int G_ = tid + i_ * 512; int row_ = G_ >> 2;                        \
          int gs_ = (G_ & 3) ^ ((row_ >> 1) & 3);                             \
          gload_lds16(E2 + (size_t)(ct_ + row_) * K2 + kb_ + gs_ * 8,         \
                      &BsR[sl_][G_ * 8]);                                     \
      } }

    // prologue: stage subtiles 0,1,2 (12 loads in flight)
    STAGE_SUBT(0);
    STAGE_SUBT(1);
    STAGE_SUBT(2);

    int sgi = 0;
    for (int cti = 0; cti < CT_PER_SPLIT; ++cti) {
        const int ct0 = col0 + cti * 256;
        f32x4 acc[4][8];
#pragma unroll
        for (int m = 0; m < 4; ++m)
#pragma unroll
            for (int n = 0; n < 8; ++n) acc[m][n] = (f32x4){0.f, 0.f, 0.f, 0.f};

#pragma unroll 4
        for (int s = 0; s < SUBT_PER_CTI; ++s, ++sgi) {
            const int slot = sgi & 3;
            // counted wait: own share of subtile sgi has landed
            if (sgi < SUBT_TOTAL - 2) {
                asm volatile("s_waitcnt vmcnt(8)" ::: "memory");
            } else if (sgi == SUBT_TOTAL - 2) {
                asm volatile("s_waitcnt vmcnt(4)" ::: "memory");
            } else {
                asm volatile("s_waitcnt vmcnt(0)" ::: "memory");
            }
            // stage subtile sgi+3 into slot (sgi+3)&3 = (sgi-1)&3
            // (freed by previous phase's post-lgkm barrier)
            if (sgi + 3 < SUBT_TOTAL) { STAGE_SUBT(sgi + 3); }
            __builtin_amdgcn_s_barrier();          // all waves' subtile sgi landed
            __builtin_amdgcn_sched_barrier(0);

            short8v af[4], bf[4];
#pragma unroll
            for (int m = 0; m < 4; ++m) {
                int row = wm * 64 + m * 16 + c;
                int g   = qh ^ ((row >> 1) & 3);
                af[m] = *(const short8v*)&AsR[slot][row * 32 + g * 8];
            }
#pragma unroll
            for (int n = 0; n < 4; ++n) {
                int rb = wn * 128 + n * 16 + c;
                int g  = qh ^ ((rb >> 1) & 3);
                bf[n] = *(const short8v*)&BsR[slot][rb * 32 + g * 8];
            }
            asm volatile("s_waitcnt lgkmcnt(0)" ::: "memory");
            __builtin_amdgcn_sched_barrier(0);
            __builtin_amdgcn_s_setprio(1);
#pragma unroll
            for (int m = 0; m < 4; ++m)
#pragma unroll
                for (int n = 0; n < 4; ++n)
                    acc[m][n] = __builtin_amdgcn_mfma_f32_16x16x32_bf16(
                        af[m], bf[n], acc[m][n], 0, 0, 0);
            __builtin_amdgcn_s_setprio(0);
#pragma unroll
            for (int n = 0; n < 4; ++n) {
                int rb = wn * 128 + (n + 4) * 16 + c;
                int g  = qh ^ ((rb >> 1) & 3);
                bf[n] = *(const short8v*)&BsR[slot][rb * 32 + g * 8];
            }
            asm volatile("s_waitcnt lgkmcnt(0)" ::: "memory");
            __builtin_amdgcn_sched_barrier(0);
            __builtin_amdgcn_s_setprio(1);
#pragma unroll
            for (int m = 0; m < 4; ++m)
#pragma unroll
                for (int n = 0; n < 4; ++n)
                    acc[m][n + 4] = __builtin_amdgcn_mfma_f32_16x16x32_bf16(
                        af[m], bf[n], acc[m][n + 4], 0, 0, 0);
            __builtin_amdgcn_s_setprio(0);
            __builtin_amdgcn_sched_barrier(0);
            asm volatile("" ::: "memory");
            __builtin_amdgcn_s_barrier();          // reads of this slot done
        }

        // fold this 256-col tile into running per-lane top-2
#pragma unroll
        for (int m = 0; m < 4; ++m)
#pragma unroll
            for (int n = 0; n < 8; ++n) {
                int col = ct0 + wn * 128 + n * 16 + c;
#pragma unroll
                for (int r = 0; r < 4; ++r) {
                    float sv = acc[m][n][r];
                    int slot2 = m * 4 + r;
                    if (sv > v1[slot2]) { v2[slot2] = v1[slot2]; v1[slot2] = sv; i1[slot2] = col; }
                    else if (sv > v2[slot2]) v2[slot2] = sv;
                }
            }
    }
#undef STAGE_SUBT

    // cross-lane merge over the 16 col-lanes (rows fixed per (qh,slot))
#pragma unroll
    for (int s = 0; s < 16; ++s) {
        float a1 = v1[s], a2 = v2[s]; int ai = i1[s];
#pragma unroll
        for (int off = 1; off < 16; off <<= 1) {
            float o1 = __shfl_xor(a1, off);
            float o2 = __shfl_xor(a2, off);
            int   oi = __shfl_xor(ai, off);
            if (o1 > a1 || (o1 == a1 && oi < ai)) {
                a2 = fmaxf(a1, o2); a1 = o1; ai = oi;
            } else {
                a2 = fmaxf(a2, o1);   // tie with larger idx -> gap 0 -> fallback
            }
        }
        v1[s] = a1; v2[s] = a2; i1[s] = ai;
    }
    // merge the two wn-waves (same rows, different col halves) via LDS
    if (c == 0 && wn == 1) {
#pragma unroll
        for (int s = 0; s < 16; ++s) {
            int li = wm * 64 + qh * 16 + s;
            smv1[li] = v1[s]; smv2[li] = v2[s]; smi[li] = i1[s];
        }
    }
    __syncthreads();
    if (c == 0 && wn == 0) {
#pragma unroll
        for (int s = 0; s < 16; ++s) {
            int li = wm * 64 + qh * 16 + s;
            float o1 = smv1[li], o2 = smv2[li]; int oi = smi[li];
            if (o1 > v1[s] || (o1 == v1[s] && oi < i1[s])) {
                v2[s] = fmaxf(v1[s], o2); v1[s] = o1; i1[s] = oi;
            } else {
                v2[s] = fmaxf(v2[s], o1);
            }
            int row = (int)grow0 + wm * 64 + (s >> 2) * 16 + qh * 4 + (s & 3);
            partials[(size_t)row * 4 + split] =
                make_float4(v1[s], v2[s], __int_as_float(i1[s]), 0.f);
        }
    }
}

// ---------- combine split-partials, gap test, enqueue fallback ----------
__global__ __launch_bounds__(256) void combine_kernel(
    const float4* __restrict__ partials, int* __restrict__ ind,
    int* __restrict__ fb_count, int* __restrict__ fb_rows,
    unsigned long long* __restrict__ best) {
    int row = blockIdx.x * 256 + threadIdx.x;
    if (row >= MROWS) return;
    float g1 = -3.0e38f, g2 = -3.0e38f; int gi = 0;
#pragma unroll
    for (int s = 0; s < NSPLIT; ++s) {
        float4 p = partials[(size_t)row * 4 + s];
        if (p.x > g1 || (p.x == g1 && __float_as_int(p.z) < gi)) {
            g2 = fmaxf(g1, p.y); g1 = p.x; gi = __float_as_int(p.z);
        } else {
            g2 = fmaxf(g2, p.x);
        }
    }
    ind[row] = gi;
    if (g1 - g2 <= TAU) {
        int k = atomicAdd(fb_count, 1);
        fb_rows[k] = row;
        best[row] = 0ull;
    }
}

// ---------- exact f32 rescore for flagged rows ----------
__global__ __launch_bounds__(256) void fallback_kernel(
    const float* __restrict__ x, const float* __restrict__ embed,
    const float* __restrict__ inv_norm, const int* __restrict__ fb_count,
    const int* __restrict__ fb_rows, unsigned long long* __restrict__ best) {
    __shared__ float es[16][D];
    __shared__ float xs[D];
    const int t = threadIdx.x;
    const int c0 = blockIdx.x * 16;
    for (int i = t; i < 16 * 128; i += 256) {
        int col = i >> 7, f4 = i & 127;
        *(float4*)&es[col][f4 * 4] =
            *(const float4*)&embed[(size_t)(c0 + col) * D + f4 * 4];
    }
    const int nfb = *fb_count;
    const int col = t >> 4, s = t & 15;
    for (int ri = 0; ri < nfb; ++ri) {
        int row = fb_rows[ri];
        __syncthreads();
        if (t < 128)
            *(float4*)&xs[t * 4] = *(const float4*)&x[(size_t)row * D + t * 4];
        __syncthreads();
        float dot = 0.f;
        const float* ep = &es[col][s * 32];
        const float* xp = &xs[s * 32];
#pragma unroll
        for (int k = 0; k < 8; ++k) {
            float4 a = *(const float4*)&xp[k * 4];
            float4 b = *(const float4*)&ep[k * 4];
            dot = fmaf(a.x, b.x, fmaf(a.y, b.y, fmaf(a.z, b.z, fmaf(a.w, b.w, dot))));
        }
        dot += __shfl_xor(dot, 1); dot += __shfl_xor(dot, 2);
        dot += __shfl_xor(dot, 4); dot += __shfl_xor(dot, 8);
        if (s == 0) {
            float score = dot * inv_norm[c0 + col];
            unsigned fb = __float_as_uint(score);
            fb = (fb & 0x80000000u) ? ~fb : (fb | 0x80000000u);
            unsigned long long key = ((unsigned long long)fb << 32) |
                (unsigned long long)(0xFFFFFFFFu - (unsigned)(c0 + col));
            atomicMax(best + row, key);
        }
    }
}

__global__ void fbwrite_kernel(const int* __restrict__ fb_count,
                               const int* __restrict__ fb_rows,
                               const unsigned long long* __restrict__ best,
                               int* __restrict__ ind) {
    int n = *fb_count;
    for (int i = threadIdx.x; i < n; i += 256) {
        int row = fb_rows[i];
        unsigned long long k = best[row];
        ind[row] = (int)(0xFFFFFFFFu - (unsigned)(k & 0xFFFFFFFFull));
    }
}

// ---------- gather ----------
__global__ __launch_bounds__(128) void gather_kernel(
    const float* __restrict__ embed, const int* __restrict__ ind,
    float* __restrict__ out_q, float* __restrict__ out_i) {
    int row = blockIdx.x;
    int t = threadIdx.x;
    int idx = ind[row];
    const float4* src = reinterpret_cast<const float4*>(embed + (size_t)idx * D);
    float4* dst = reinterpret_cast<float4*>(out_q + (size_t)row * D);
    dst[t] = src[t];
    if (t == 0) out_i[row] = (float)idx;
}

// ================= legacy f32 path (used if ws too small) =================
#define BM 64
#define BN 128
#define BK 32
#define LDX (BM + 4)
#define LDE (BN + 4)

__global__ __launch_bounds__(64) void norm_kernel(const float* __restrict__ embed,
                                                  float* __restrict__ inv_norm) {
    int cb = blockIdx.x, lane = threadIdx.x;
    const float4* r4 = reinterpret_cast<const float4*>(embed + (size_t)cb * D);
    float4 a = r4[lane], b = r4[lane + 64];
    float s = a.x*a.x + a.y*a.y + a.z*a.z + a.w*a.w
            + b.x*b.x + b.y*b.y + b.z*b.z + b.w*b.w;
#pragma unroll
    for (int off = 32; off > 0; off >>= 1) s += __shfl_xor(s, off);
    if (lane == 0) inv_norm[cb] = 1.0f / fmaxf(sqrtf(s), 1e-12f);
}

__global__ __launch_bounds__(256) void gemm_argmax_kernel(
    const float* __restrict__ x, const float* __restrict__ embed,
    const float* __restrict__ inv_norm, int* __restrict__ ind, int C) {
    __shared__ float xs[BK][LDX];
    __shared__ float es[BK][LDE];
    const int tid = threadIdx.x;
    const int tx = tid & 15;
    const int ty = tid >> 4;
    const int row0 = blockIdx.x * BM;
    float bestv[4]; int besti[4];
#pragma unroll
    for (int i = 0; i < 4; ++i) { bestv[i] = -3.0e38f; besti[i] = 0; }
    for (int ct = 0; ct < C; ct += BN) {
        float acc[4][8];
#pragma unroll
        for (int i = 0; i < 4; ++i)
#pragma unroll
            for (int j = 0; j < 8; ++j) acc[i][j] = 0.0f;
        for (int kt = 0; kt < D; kt += BK) {
#pragma unroll
            for (int i = 0; i < 2; ++i) {
                int f = tid + i * 256;
                int r = f >> 3, kq = (f & 7) << 2;
                float4 v = *reinterpret_cast<const float4*>(
                    x + (size_t)(row0 + r) * D + kt + kq);
                xs[kq+0][r]=v.x; xs[kq+1][r]=v.y; xs[kq+2][r]=v.z; xs[kq+3][r]=v.w;
            }
#pragma unroll
            for (int i = 0; i < 4; ++i) {
                int f = tid + i * 256;
                int r = f >> 3, kq = (f & 7) << 2;
                float4 v = *reinterpret_cast<const float4*>(
                    embed + (size_t)(ct + r) * D + kt + kq);
                es[kq+0][r]=v.x; es[kq+1][r]=v.y; es[kq+2][r]=v.z; es[kq+3][r]=v.w;
            }
            __syncthreads();
#pragma unroll
            for (int k = 0; k < BK; ++k) {
                float4 a4 = *reinterpret_cast<const float4*>(&xs[k][ty * 4]);
                float4 b0 = *reinterpret_cast<const float4*>(&es[k][tx * 8]);
                float4 b1 = *reinterpret_cast<const float4*>(&es[k][tx * 8 + 4]);
                float a[4] = {a4.x, a4.y, a4.z, a4.w};
                float b[8] = {b0.x, b0.y, b0.z, b0.w, b1.x, b1.y, b1.z, b1.w};
#pragma unroll
                for (int i = 0; i < 4; ++i)
#pragma unroll
                    for (int j = 0; j < 8; ++j)
                        acc[i][j] = fmaf(a[i], b[j], acc[i][j]);
            }
            __syncthreads();
        }
#pragma unroll
        for (int i = 0; i < 4; ++i) {
            float v = -3.0e38f; int vi = 0;
#pragma unroll
            for (int j = 0; j < 8; ++j) {
                int col = ct + tx * 8 + j;
                float s = acc[i][j] * inv_norm[col];
                if (s > v) { v = s; vi = col; }
            }
#pragma unroll
            for (int off = 1; off < 16; off <<= 1) {
                float ov = __shfl_xor(v, off, 16);
                int   oi = __shfl_xor(vi, off, 16);
                if (ov > v || (ov == v && oi < vi)) { v = ov; vi = oi; }
            }
            if (v > bestv[i] || (v == bestv[i] && vi < besti[i])) {
                bestv[i] = v; besti[i] = vi;
            }
        }
    }
    if (tx == 0) {
#pragma unroll
        for (int i = 0; i < 4; ++i) ind[row0 + ty * 4 + i] = besti[i];
    }
}

// =========================================================================
extern "C" void kernel_launch(void* const* d_in, const int* in_sizes, int n_in,
                              void* d_out, int out_size, void* d_ws, size_t ws_size,
                              hipStream_t stream) {
    const float* x     = (const float*)d_in[0];
    const float* embed = (const float*)d_in[1];
    const int M = in_sizes[0] / D;   // 32768
    const int C = in_sizes[1] / D;   // 8192

    float* out_q = (float*)d_out;
    float* out_i = (float*)d_out + (size_t)M * D;

    // workspace layout for the MFMA path
    size_t X2_off   = 0;
    size_t X2_sz    = (size_t)M * K2 * 2;
    size_t E2_off   = X2_off + X2_sz;
    size_t E2_sz    = (size_t)C * K2 * 2;
    size_t inv_off  = E2_off + E2_sz;
    size_t inv_sz   = (size_t)C * 4;
    size_t part_off = inv_off + inv_sz;
    size_t part_sz  = (size_t)M * 4 * 16;
    size_t ind_off  = part_off + part_sz;
    size_t ind_sz   = (size_t)M * 4;
    size_t fbc_off  = ind_off + ind_sz;
    size_t fbr_off  = fbc_off + 16;
    size_t fbr_sz   = (size_t)M * 4;
    size_t best_off = fbr_off + fbr_sz;
    size_t total    = best_off + (size_t)M * 8;

    if (ws_size >= total && M == MROWS && C == CCOLS) {
        char* ws = (char*)d_ws;
        unsigned short* X2 = (unsigned short*)(ws + X2_off);
        unsigned short* E2 = (unsigned short*)(ws + E2_off);
        float* inv_norm    = (float*)(ws + inv_off);
        float4* partials   = (float4*)(ws + part_off);
        int* ind           = (int*)(ws + ind_off);
        int* fb_count      = (int*)(ws + fbc_off);
        int* fb_rows       = (int*)(ws + fbr_off);
        unsigned long long* best = (unsigned long long*)(ws + best_off);

        hipMemsetAsync(fb_count, 0, 16, stream);
        prep_embed_kernel<<<C, 64, 0, stream>>>(embed, E2, inv_norm);
        prep_x_kernel<<<M, 64, 0, stream>>>(x, X2);
        gemm_topk4_kernel<<<(M / 256) * NSPLIT, 512, 0, stream>>>(X2, E2, partials);
        combine_kernel<<<M / 256, 256, 0, stream>>>(partials, ind, fb_count, fb_rows, best);
        fallback_kernel<<<C / 16, 256, 0, stream>>>(x, embed, inv_norm, fb_count, fb_rows, best);
        fbwrite_kernel<<<1, 256, 0, stream>>>(fb_count, fb_rows, best, ind);
        gather_kernel<<<M, 128, 0, stream>>>(embed, ind, out_q, out_i);
    } else {
        float* inv_norm = (float*)d_ws;
        int*   ind      = (int*)d_ws + C;
        norm_kernel<<<C, 64, 0, stream>>>(embed, inv_norm);
        gemm_argmax_kernel<<<M / BM, 256, 0, stream>>>(x, embed, inv_norm, ind, C);
        gather_kernel<<<M, 128, 0, stream>>>(embed, ind, out_q, out_i);
    }
}

// Round 10
// 1155.220 us; speedup vs baseline: 5.1190x; 1.0317x over previous
//
#include <hip/hip_runtime.h>
#include <math.h>

#define D 512
#define MROWS 32768
#define CCOLS 8192
#define K2 1536
#define NT 24            // K-tiles of 64
#define NSPLIT 2
#define CT_PER_SPLIT 16  // 4096 cols / 256
#define SUBT_PER_CTI (NT * 2)                 // 48 subtiles (k=32) per col-tile
#define SUBT_TOTAL (CT_PER_SPLIT * SUBT_PER_CTI)  // 768
#define TAU 2.0e-4f

typedef __attribute__((ext_vector_type(8))) short short8v;
typedef __attribute__((ext_vector_type(4))) float f32x4;

__device__ __forceinline__ unsigned short f2bf_rne(float f) {
    unsigned u = __float_as_uint(f);
    unsigned r = ((u >> 16) & 1u) + 0x7FFFu;
    return (unsigned short)((u + r) >> 16);
}
__device__ __forceinline__ float bf2f(unsigned short h) {
    return __uint_as_float(((unsigned)h) << 16);
}

__device__ __forceinline__ void gload_lds16(const void* gsrc, void* ldst) {
    __builtin_amdgcn_global_load_lds(
        (const __attribute__((address_space(1))) unsigned int*)gsrc,
        (__attribute__((address_space(3))) unsigned int*)ldst, 16, 0, 0);
}

// ---------- prep: codebook -> inv_norm + E2 = [hi(e_n) | lo(e_n) | hi(e_n)] ----------
__global__ __launch_bounds__(64) void prep_embed_kernel(
    const float* __restrict__ embed, unsigned short* __restrict__ E2,
    float* __restrict__ inv_norm) {
    int cb = blockIdx.x, lane = threadIdx.x;
    const float4* r4 = reinterpret_cast<const float4*>(embed + (size_t)cb * D);
    float4 a = r4[lane], b = r4[lane + 64];
    float ss = a.x*a.x + a.y*a.y + a.z*a.z + a.w*a.w
             + b.x*b.x + b.y*b.y + b.z*b.z + b.w*b.w;
#pragma unroll
    for (int off = 32; off > 0; off >>= 1) ss += __shfl_xor(ss, off);
    float inv = 1.0f / fmaxf(sqrtf(ss), 1e-12f);
    if (lane == 0) inv_norm[cb] = inv;
    float ea[4] = {a.x*inv, a.y*inv, a.z*inv, a.w*inv};
    float eb[4] = {b.x*inv, b.y*inv, b.z*inv, b.w*inv};
    ushort4 ha, la, hb, lb;
    { for (int j=0;j<4;++j) (&ha.x)[j] = f2bf_rne(ea[j]); }
    { for (int j=0;j<4;++j) (&la.x)[j] = f2bf_rne(ea[j] - bf2f((&ha.x)[j])); }
    { for (int j=0;j<4;++j) (&hb.x)[j] = f2bf_rne(eb[j]); }
    { for (int j=0;j<4;++j) (&lb.x)[j] = f2bf_rne(eb[j] - bf2f((&hb.x)[j])); }
    unsigned short* row = E2 + (size_t)cb * K2;
    int k = lane * 4;
    *(ushort4*)&row[k]          = ha;  // hi  at [0,512)
    *(ushort4*)&row[256 + k]    = hb;
    *(ushort4*)&row[512 + k]    = la;  // lo  at [512,1024)
    *(ushort4*)&row[768 + k]    = lb;
    *(ushort4*)&row[1024 + k]   = ha;  // hi  at [1024,1536)
    *(ushort4*)&row[1280 + k]   = hb;
}

// ---------- prep: x -> X2 = [hi(x) | hi(x) | lo(x)] ----------
__global__ __launch_bounds__(64) void prep_x_kernel(
    const float* __restrict__ x, unsigned short* __restrict__ X2) {
    int rb = blockIdx.x, lane = threadIdx.x;
    const float4* r4 = reinterpret_cast<const float4*>(x + (size_t)rb * D);
    float4 a = r4[lane], b = r4[lane + 64];
    float ea[4] = {a.x, a.y, a.z, a.w};
    float eb[4] = {b.x, b.y, b.z, b.w};
    ushort4 ha, la, hb, lb;
    { for (int j=0;j<4;++j) (&ha.x)[j] = f2bf_rne(ea[j]); }
    { for (int j=0;j<4;++j) (&la.x)[j] = f2bf_rne(ea[j] - bf2f((&ha.x)[j])); }
    { for (int j=0;j<4;++j) (&hb.x)[j] = f2bf_rne(eb[j]); }
    { for (int j=0;j<4;++j) (&lb.x)[j] = f2bf_rne(eb[j] - bf2f((&hb.x)[j])); }
    unsigned short* row = X2 + (size_t)rb * K2;
    int k = lane * 4;
    *(ushort4*)&row[k]        = ha;   // hi
    *(ushort4*)&row[256 + k]  = hb;
    *(ushort4*)&row[512 + k]  = ha;   // hi again
    *(ushort4*)&row[768 + k]  = hb;
    *(ushort4*)&row[1024 + k] = la;   // lo
    *(ushort4*)&row[1280 + k] = lb;
}

// ---------- 256x256-tile bf16 GEMM + per-row top-2, subtile-ring pipeline ----------
// 512 threads = 8 waves (4M x 2N). K split into k=32 subtiles; 4-slot LDS ring.
// ONE barrier + ONE counted vmcnt per phase:
//   barrier -> sched_barrier -> ds_reads + MFMA (compiler-scheduled lgkm waits)
//   -> STAGE(S+3 into slot (S-1)&3) -> vmcnt(8)  [drains S+1's loads]
// Invariant entering phase S: outstanding = {S+1,S+2} (8 loads), S complete.
// Slot safety: stage target (S-1)&3 readers finished before THIS barrier;
// never aliases this phase's read slot S&3.
__global__ __launch_bounds__(512, 2) void gemm_topk5_kernel(
    const unsigned short* __restrict__ X2, const unsigned short* __restrict__ E2,
    float4* __restrict__ partials) {
    __shared__ __align__(16) unsigned short AsR[4][256 * 32];
    __shared__ __align__(16) unsigned short BsR[4][256 * 32];
    __shared__ float smv1[256], smv2[256];
    __shared__ int   smi[256];

    const int tid  = threadIdx.x;
    const int lane = tid & 63;
    const int w    = tid >> 6;          // 0..7
    const int wm   = w >> 1;            // 0..3 (row group of 64)
    const int wn   = w & 1;             // 0..1 (col group of 128)
    const int c    = lane & 15;
    const int qh   = lane >> 4;         // k-granule 0..3

    // bijective XCD-contiguous mapping: XCD x owns logical [x*32, x*32+32)
    const int bid     = blockIdx.x;
    const int logical = (bid & 7) * 32 + (bid >> 3);
    const int split   = logical >> 7;        // 0..1
    const int rowtile = logical & 127;       // 0..127
    const size_t grow0 = (size_t)rowtile * 256;
    const int col0     = split * (CT_PER_SPLIT * 256);

    float v1[16], v2[16]; int i1[16];
#pragma unroll
    for (int s = 0; s < 16; ++s) { v1[s] = -3.0e38f; v2[s] = -3.0e38f; i1[s] = 0; }

    // stage subtile S: 4 gload_lds/thread into ring slot S&3.
    // Source granule pre-swizzled (G&3)^((row>>1)&3) (both-sides involution).
#define STAGE_SUBT(S)                                                         \
    { int cti_ = (S) / SUBT_PER_CTI;                                          \
      int rem_ = (S) - cti_ * SUBT_PER_CTI;                                   \
      int kb_  = (rem_ >> 1) * 64 + (rem_ & 1) * 32;                          \
      int ct_  = col0 + cti_ * 256;                                           \
      int sl_  = (S) & 3;                                                     \
      _Pragma("unroll")                                                       \
      for (int i_ = 0; i_ < 2; ++i_) {                                        \
          int G_ = tid + i_ * 512; int row_ = G_ >> 2;                        \
          int gs_ = (G_ & 3) ^ ((row_ >> 1) & 3);                             \
          gload_lds16(X2 + (grow0 + row_) * (size_t)K2 + kb_ + gs_ * 8,       \
                      &AsR[sl_][G_ * 8]);                                     \
      }                                                                       \
      _Pragma("unroll")                                                       \
      for (int i_ = 0; i_ < 2; ++i_) {                                        \
          int G_ = tid + i_ * 512; int row_ = G_ >> 2;                        \
          int gs_ = (G_ & 3) ^ ((row_ >> 1) & 3);                             \
          gload_lds16(E2 + (size_t)(ct_ + row_) * K2 + kb_ + gs_ * 8,         \
                      &BsR[sl_][G_ * 8]);                                     \
      } }

    // prologue: stage subtiles 0,1,2 (12 loads); drain subtile 0
    STAGE_SUBT(0);
    STAGE_SUBT(1);
    STAGE_SUBT(2);
    asm volatile("s_waitcnt vmcnt(8)" ::: "memory");

    int sgi = 0;
    for (int cti = 0; cti < CT_PER_SPLIT; ++cti) {
        const int ct0 = col0 + cti * 256;
        f32x4 acc[4][8];
#pragma unroll
        for (int m = 0; m < 4; ++m)
#pragma unroll
            for (int n = 0; n < 8; ++n) acc[m][n] = (f32x4){0.f, 0.f, 0.f, 0.f};

#pragma unroll 4
        for (int s = 0; s < SUBT_PER_CTI; ++s, ++sgi) {
            const int slot = sgi & 3;
            __builtin_amdgcn_s_barrier();          // subtile sgi valid for all waves
            __builtin_amdgcn_sched_barrier(0);     // nothing hoists above it

            short8v af[4], bf[4];
#pragma unroll
            for (int m = 0; m < 4; ++m) {
                int row = wm * 64 + m * 16 + c;
                int g   = qh ^ ((row >> 1) & 3);
                af[m] = *(const short8v*)&AsR[slot][row * 32 + g * 8];
            }
#pragma unroll
            for (int n = 0; n < 4; ++n) {
                int rb = wn * 128 + n * 16 + c;
                int g  = qh ^ ((rb >> 1) & 3);
                bf[n] = *(const short8v*)&BsR[slot][rb * 32 + g * 8];
            }
            __builtin_amdgcn_s_setprio(1);
#pragma unroll
            for (int m = 0; m < 4; ++m)
#pragma unroll
                for (int n = 0; n < 4; ++n)
                    acc[m][n] = __builtin_amdgcn_mfma_f32_16x16x32_bf16(
                        af[m], bf[n], acc[m][n], 0, 0, 0);
            __builtin_amdgcn_s_setprio(0);
#pragma unroll
            for (int n = 0; n < 4; ++n) {
                int rb = wn * 128 + (n + 4) * 16 + c;
                int g  = qh ^ ((rb >> 1) & 3);
                bf[n] = *(const short8v*)&BsR[slot][rb * 32 + g * 8];
            }
            __builtin_amdgcn_s_setprio(1);
#pragma unroll
            for (int m = 0; m < 4; ++m)
#pragma unroll
                for (int n = 0; n < 4; ++n)
                    acc[m][n + 4] = __builtin_amdgcn_mfma_f32_16x16x32_bf16(
                        af[m], bf[n], acc[m][n + 4], 0, 0, 0);
            __builtin_amdgcn_s_setprio(0);

            // stage 3 ahead, then counted drain of subtile sgi+1
            if (sgi + 3 < SUBT_TOTAL) {
                STAGE_SUBT(sgi + 3);
                asm volatile("s_waitcnt vmcnt(8)" ::: "memory");
            } else if (sgi == SUBT_TOTAL - 3) {
                asm volatile("s_waitcnt vmcnt(4)" ::: "memory");
            } else if (sgi == SUBT_TOTAL - 2) {
                asm volatile("s_waitcnt vmcnt(0)" ::: "memory");
            }
        }

        // fold this 256-col tile into running per-lane top-2
#pragma unroll
        for (int m = 0; m < 4; ++m)
#pragma unroll
            for (int n = 0; n < 8; ++n) {
                int col = ct0 + wn * 128 + n * 16 + c;
#pragma unroll
                for (int r = 0; r < 4; ++r) {
                    float sv = acc[m][n][r];
                    int slot2 = m * 4 + r;
                    if (sv > v1[slot2]) { v2[slot2] = v1[slot2]; v1[slot2] = sv; i1[slot2] = col; }
                    else if (sv > v2[slot2]) v2[slot2] = sv;
                }
            }
    }
#undef STAGE_SUBT

    // cross-lane merge over the 16 col-lanes (rows fixed per (qh,slot))
#pragma unroll
    for (int s = 0; s < 16; ++s) {
        float a1 = v1[s], a2 = v2[s]; int ai = i1[s];
#pragma unroll
        for (int off = 1; off < 16; off <<= 1) {
            float o1 = __shfl_xor(a1, off);
            float o2 = __shfl_xor(a2, off);
            int   oi = __shfl_xor(ai, off);
            if (o1 > a1 || (o1 == a1 && oi < ai)) {
                a2 = fmaxf(a1, o2); a1 = o1; ai = oi;
            } else {
                a2 = fmaxf(a2, o1);   // tie with larger idx -> gap 0 -> fallback
            }
        }
        v1[s] = a1; v2[s] = a2; i1[s] = ai;
    }
    // merge the two wn-waves (same rows, different col halves) via LDS
    if (c == 0 && wn == 1) {
#pragma unroll
        for (int s = 0; s < 16; ++s) {
            int li = wm * 64 + qh * 16 + s;
            smv1[li] = v1[s]; smv2[li] = v2[s]; smi[li] = i1[s];
        }
    }
    __syncthreads();
    if (c == 0 && wn == 0) {
#pragma unroll
        for (int s = 0; s < 16; ++s) {
            int li = wm * 64 + qh * 16 + s;
            float o1 = smv1[li], o2 = smv2[li]; int oi = smi[li];
            if (o1 > v1[s] || (o1 == v1[s] && oi < i1[s])) {
                v2[s] = fmaxf(v1[s], o2); v1[s] = o1; i1[s] = oi;
            } else {
                v2[s] = fmaxf(v2[s], o1);
            }
            int row = (int)grow0 + wm * 64 + (s >> 2) * 16 + qh * 4 + (s & 3);
            partials[(size_t)row * 4 + split] =
                make_float4(v1[s], v2[s], __int_as_float(i1[s]), 0.f);
        }
    }
}

// ---------- combine split-partials, gap test, enqueue fallback ----------
__global__ __launch_bounds__(256) void combine_kernel(
    const float4* __restrict__ partials, int* __restrict__ ind,
    int* __restrict__ fb_count, int* __restrict__ fb_rows,
    unsigned long long* __restrict__ best) {
    int row = blockIdx.x * 256 + threadIdx.x;
    if (row >= MROWS) return;
    float g1 = -3.0e38f, g2 = -3.0e38f; int gi = 0;
#pragma unroll
    for (int s = 0; s < NSPLIT; ++s) {
        float4 p = partials[(size_t)row * 4 + s];
        if (p.x > g1 || (p.x == g1 && __float_as_int(p.z) < gi)) {
            g2 = fmaxf(g1, p.y); g1 = p.x; gi = __float_as_int(p.z);
        } else {
            g2 = fmaxf(g2, p.x);
        }
    }
    ind[row] = gi;
    if (g1 - g2 <= TAU) {
        int k = atomicAdd(fb_count, 1);
        fb_rows[k] = row;
        best[row] = 0ull;
    }
}

// ---------- exact f32 rescore for flagged rows ----------
__global__ __launch_bounds__(256) void fallback_kernel(
    const float* __restrict__ x, const float* __restrict__ embed,
    const float* __restrict__ inv_norm, const int* __restrict__ fb_count,
    const int* __restrict__ fb_rows, unsigned long long* __restrict__ best) {
    __shared__ float es[16][D];
    __shared__ float xs[D];
    const int t = threadIdx.x;
    const int c0 = blockIdx.x * 16;
    for (int i = t; i < 16 * 128; i += 256) {
        int col = i >> 7, f4 = i & 127;
        *(float4*)&es[col][f4 * 4] =
            *(const float4*)&embed[(size_t)(c0 + col) * D + f4 * 4];
    }
    const int nfb = *fb_count;
    const int col = t >> 4, s = t & 15;
    for (int ri = 0; ri < nfb; ++ri) {
        int row = fb_rows[ri];
        __syncthreads();
        if (t < 128)
            *(float4*)&xs[t * 4] = *(const float4*)&x[(size_t)row * D + t * 4];
        __syncthreads();
        float dot = 0.f;
        const float* ep = &es[col][s * 32];
        const float* xp = &xs[s * 32];
#pragma unroll
        for (int k = 0; k < 8; ++k) {
            float4 a = *(const float4*)&xp[k * 4];
            float4 b = *(const float4*)&ep[k * 4];
            dot = fmaf(a.x, b.x, fmaf(a.y, b.y, fmaf(a.z, b.z, fmaf(a.w, b.w, dot))));
        }
        dot += __shfl_xor(dot, 1); dot += __shfl_xor(dot, 2);
        dot += __shfl_xor(dot, 4); dot += __shfl_xor(dot, 8);
        if (s == 0) {
            float score = dot * inv_norm[c0 + col];
            unsigned fb = __float_as_uint(score);
            fb = (fb & 0x80000000u) ? ~fb : (fb | 0x80000000u);
            unsigned long long key = ((unsigned long long)fb << 32) |
                (unsigned long long)(0xFFFFFFFFu - (unsigned)(c0 + col));
            atomicMax(best + row, key);
        }
    }
}

__global__ void fbwrite_kernel(const int* __restrict__ fb_count,
                               const int* __restrict__ fb_rows,
                               const unsigned long long* __restrict__ best,
                               int* __restrict__ ind) {
    int n = *fb_count;
    for (int i = threadIdx.x; i < n; i += 256) {
        int row = fb_rows[i];
        unsigned long long k = best[row];
        ind[row] = (int)(0xFFFFFFFFu - (unsigned)(k & 0xFFFFFFFFull));
    }
}

// ---------- gather ----------
__global__ __launch_bounds__(128) void gather_kernel(
    const float* __restrict__ embed, const int* __restrict__ ind,
    float* __restrict__ out_q, float* __restrict__ out_i) {
    int row = blockIdx.x;
    int t = threadIdx.x;
    int idx = ind[row];
    const float4* src = reinterpret_cast<const float4*>(embed + (size_t)idx * D);
    float4* dst = reinterpret_cast<float4*>(out_q + (size_t)row * D);
    dst[t] = src[t];
    if (t == 0) out_i[row] = (float)idx;
}

// ================= legacy f32 path (used if ws too small) =================
#define BM 64
#define BN 128
#define BK 32
#define LDX (BM + 4)
#define LDE (BN + 4)

__global__ __launch_bounds__(64) void norm_kernel(const float* __restrict__ embed,
                                                  float* __restrict__ inv_norm) {
    int cb = blockIdx.x, lane = threadIdx.x;
    const float4* r4 = reinterpret_cast<const float4*>(embed + (size_t)cb * D);
    float4 a = r4[lane], b = r4[lane + 64];
    float s = a.x*a.x + a.y*a.y + a.z*a.z + a.w*a.w
            + b.x*b.x + b.y*b.y + b.z*b.z + b.w*b.w;
#pragma unroll
    for (int off = 32; off > 0; off >>= 1) s += __shfl_xor(s, off);
    if (lane == 0) inv_norm[cb] = 1.0f / fmaxf(sqrtf(s), 1e-12f);
}

__global__ __launch_bounds__(256) void gemm_argmax_kernel(
    const float* __restrict__ x, const float* __restrict__ embed,
    const float* __restrict__ inv_norm, int* __restrict__ ind, int C) {
    __shared__ float xs[BK][LDX];
    __shared__ float es[BK][LDE];
    const int tid = threadIdx.x;
    const int tx = tid & 15;
    const int ty = tid >> 4;
    const int row0 = blockIdx.x * BM;
    float bestv[4]; int besti[4];
#pragma unroll
    for (int i = 0; i < 4; ++i) { bestv[i] = -3.0e38f; besti[i] = 0; }
    for (int ct = 0; ct < C; ct += BN) {
        float acc[4][8];
#pragma unroll
        for (int i = 0; i < 4; ++i)
#pragma unroll
            for (int j = 0; j < 8; ++j) acc[i][j] = 0.0f;
        for (int kt = 0; kt < D; kt += BK) {
#pragma unroll
            for (int i = 0; i < 2; ++i) {
                int f = tid + i * 256;
                int r = f >> 3, kq = (f & 7) << 2;
                float4 v = *reinterpret_cast<const float4*>(
                    x + (size_t)(row0 + r) * D + kt + kq);
                xs[kq+0][r]=v.x; xs[kq+1][r]=v.y; xs[kq+2][r]=v.z; xs[kq+3][r]=v.w;
            }
#pragma unroll
            for (int i = 0; i < 4; ++i) {
                int f = tid + i * 256;
                int r = f >> 3, kq = (f & 7) << 2;
                float4 v = *reinterpret_cast<const float4*>(
                    embed + (size_t)(ct + r) * D + kt + kq);
                es[kq+0][r]=v.x; es[kq+1][r]=v.y; es[kq+2][r]=v.z; es[kq+3][r]=v.w;
            }
            __syncthreads();
#pragma unroll
            for (int k = 0; k < BK; ++k) {
                float4 a4 = *reinterpret_cast<const float4*>(&xs[k][ty * 4]);
                float4 b0 = *reinterpret_cast<const float4*>(&es[k][tx * 8]);
                float4 b1 = *reinterpret_cast<const float4*>(&es[k][tx * 8 + 4]);
                float a[4] = {a4.x, a4.y, a4.z, a4.w};
                float b[8] = {b0.x, b0.y, b0.z, b0.w, b1.x, b1.y, b1.z, b1.w};
#pragma unroll
                for (int i = 0; i < 4; ++i)
#pragma unroll
                    for (int j = 0; j < 8; ++j)
                        acc[i][j] = fmaf(a[i], b[j], acc[i][j]);
            }
            __syncthreads();
        }
#pragma unroll
        for (int i = 0; i < 4; ++i) {
            float v = -3.0e38f; int vi = 0;
#pragma unroll
            for (int j = 0; j < 8; ++j) {
                int col = ct + tx * 8 + j;
                float s = acc[i][j] * inv_norm[col];
                if (s > v) { v = s; vi = col; }
            }
#pragma unroll
            for (int off = 1; off < 16; off <<= 1) {
                float ov = __shfl_xor(v, off, 16);
                int   oi = __shfl_xor(vi, off, 16);
                if (ov > v || (ov == v && oi < vi)) { v = ov; vi = oi; }
            }
            if (v > bestv[i] || (v == bestv[i] && vi < besti[i])) {
                bestv[i] = v; besti[i] = vi;
            }
        }
    }
    if (tx == 0) {
#pragma unroll
        for (int i = 0; i < 4; ++i) ind[row0 + ty * 4 + i] = besti[i];
    }
}

// =========================================================================
extern "C" void kernel_launch(void* const* d_in, const int* in_sizes, int n_in,
                              void* d_out, int out_size, void* d_ws, size_t ws_size,
                              hipStream_t stream) {
    const float* x     = (const float*)d_in[0];
    const float* embed = (const float*)d_in[1];
    const int M = in_sizes[0] / D;   // 32768
    const int C = in_sizes[1] / D;   // 8192

    float* out_q = (float*)d_out;
    float* out_i = (float*)d_out + (size_t)M * D;

    // workspace layout for the MFMA path
    size_t X2_off   = 0;
    size_t X2_sz    = (size_t)M * K2 * 2;
    size_t E2_off   = X2_off + X2_sz;
    size_t E2_sz    = (size_t)C * K2 * 2;
    size_t inv_off  = E2_off + E2_sz;
    size_t inv_sz   = (size_t)C * 4;
    size_t part_off = inv_off + inv_sz;
    size_t part_sz  = (size_t)M * 4 * 16;
    size_t ind_off  = part_off + part_sz;
    size_t ind_sz   = (size_t)M * 4;
    size_t fbc_off  = ind_off + ind_sz;
    size_t fbr_off  = fbc_off + 16;
    size_t fbr_sz   = (size_t)M * 4;
    size_t best_off = fbr_off + fbr_sz;
    size_t total    = best_off + (size_t)M * 8;

    if (ws_size >= total && M == MROWS && C == CCOLS) {
        char* ws = (char*)d_ws;
        unsigned short* X2 = (unsigned short*)(ws + X2_off);
        unsigned short* E2 = (unsigned short*)(ws + E2_off);
        float* inv_norm    = (float*)(ws + inv_off);
        float4* partials   = (float4*)(ws + part_off);
        int* ind           = (int*)(ws + ind_off);
        int* fb_count      = (int*)(ws + fbc_off);
        int* fb_rows       = (int*)(ws + fbr_off);
        unsigned long long* best = (unsigned long long*)(ws + best_off);

        hipMemsetAsync(fb_count, 0, 16, stream);
        prep_embed_kernel<<<C, 64, 0, stream>>>(embed, E2, inv_norm);
        prep_x_kernel<<<M, 64, 0, stream>>>(x, X2);
        gemm_topk5_kernel<<<(M / 256) * NSPLIT, 512, 0, stream>>>(X2, E2, partials);
        combine_kernel<<<M / 256, 256, 0, stream>>>(partials, ind, fb_count, fb_rows, best);
        fallback_kernel<<<C / 16, 256, 0, stream>>>(x, embed, inv_norm, fb_count, fb_rows, best);
        fbwrite_kernel<<<1, 256, 0, stream>>>(fb_count, fb_rows, best, ind);
        gather_kernel<<<M, 128, 0, stream>>>(embed, ind, out_q, out_i);
    } else {
        float* inv_norm = (float*)d_ws;
        int*   ind      = (int*)d_ws + C;
        norm_kernel<<<C, 64, 0, stream>>>(embed, inv_norm);
        gemm_argmax_kernel<<<M / BM, 256, 0, stream>>>(x, embed, inv_norm, ind, C);
        gather_kernel<<<M, 128, 0, stream>>>(embed, ind, out_q, out_i);
    }
}